// Round 11
// baseline (1038.495 us; speedup 1.0000x reference)
//
#include <hip/hip_runtime.h>
#include <math.h>

#define NN 100000
#define EE 1600000
#define GG 64
#define HH 128
#define LL 4
#define CCLS 16
#define NC 100000
#define NB 49    // dst buckets of 2048 nodes
#define LDK 40   // padded LDS row stride (bf16 elems) for 32-wide K tiles
#define LDA2 136 // padded LDS row stride for full-K (128) tiles
#define LDC 260  // padded stride for the fused C1 tile (dword stride 130 ≡ 2 mod 32: ≤2-way banks)

typedef __attribute__((ext_vector_type(8))) short bf16x8;
typedef __attribute__((ext_vector_type(4))) float f32x4;

__device__ __forceinline__ unsigned short f2bf(float x) {
  union { float f; unsigned int u; } v; v.f = x;
  unsigned int r = v.u + 0x7fffu + ((v.u >> 16) & 1u);
  return (unsigned short)(r >> 16);
}
__device__ __forceinline__ float bl(unsigned u) {
  union { unsigned u; float f; } v; v.u = u << 16; return v.f;
}
__device__ __forceinline__ float bh(unsigned u) {
  union { unsigned u; float f; } v; v.u = u & 0xffff0000u; return v.f;
}

// ---------------- CSR build ----------------
__global__ void hist_kernel(const int* __restrict__ dst, int* __restrict__ cnt, int E) {
  int i = (blockIdx.x * 256 + threadIdx.x) * 4;
  if (i + 3 < E) {
    int4 v = *(const int4*)(dst + i);
    atomicAdd(&cnt[v.x], 1);
    atomicAdd(&cnt[v.y], 1);
    atomicAdd(&cnt[v.z], 1);
    atomicAdd(&cnt[v.w], 1);
  } else {
    for (int k = i; k < E; ++k) atomicAdd(&cnt[dst[k]], 1);
  }
}

__global__ __launch_bounds__(256) void scan_p1(const int* __restrict__ cnt,
                                               int* __restrict__ bsum, int n) {
  __shared__ int red[256];
  int tid = threadIdx.x;
  int base = blockIdx.x * 1024 + tid * 4;
  int s = 0;
  if (base + 3 < n) {
    int4 v = *(const int4*)(cnt + base);
    s = v.x + v.y + v.z + v.w;
  } else {
    for (int i = 0; i < 4; ++i) if (base + i < n) s += cnt[base + i];
  }
  red[tid] = s;
  __syncthreads();
  for (int st = 128; st >= 1; st >>= 1) {
    if (tid < st) red[tid] += red[tid + st];
    __syncthreads();
  }
  if (tid == 0) bsum[blockIdx.x] = red[0];
}

__global__ void scan_p2(int* __restrict__ bsum, int* __restrict__ rowptr,
                        int* __restrict__ bcursor, int nb, int n) {
  __shared__ int buf[128];
  int tid = threadIdx.x;
  int v = (tid < nb) ? bsum[tid] : 0;
  buf[tid] = v;
  __syncthreads();
  for (int off = 1; off < 128; off <<= 1) {
    int t = (tid >= off) ? buf[tid - off] : 0;
    __syncthreads();
    buf[tid] += t;
    __syncthreads();
  }
  if (tid < nb) bsum[tid] = buf[tid] - v;
  if (tid == 127) rowptr[n] = buf[127];
  __syncthreads();
  if (tid < NB) bcursor[tid] = bsum[2 * tid];
}

__global__ __launch_bounds__(256) void scan_p3(const int* __restrict__ cnt,
                                               const int* __restrict__ bsum,
                                               int* __restrict__ rowptr,
                                               int* __restrict__ cursor, int n) {
  __shared__ int red[256];
  int tid = threadIdx.x;
  int base = blockIdx.x * 1024 + tid * 4;
  int v[4] = {0, 0, 0, 0};
  if (base + 3 < n) {
    int4 t = *(const int4*)(cnt + base);
    v[0] = t.x; v[1] = t.y; v[2] = t.z; v[3] = t.w;
  } else {
    for (int i = 0; i < 4; ++i) if (base + i < n) v[i] = cnt[base + i];
  }
  int s = v[0] + v[1] + v[2] + v[3];
  red[tid] = s;
  __syncthreads();
  for (int off = 1; off < 256; off <<= 1) {
    int t = (tid >= off) ? red[tid - off] : 0;
    __syncthreads();
    red[tid] += t;
    __syncthreads();
  }
  int run = bsum[blockIdx.x] + red[tid] - s;
  int4 o;
  o.x = run; o.y = run + v[0]; o.z = o.y + v[1]; o.w = o.z + v[2];
  if (base + 3 < n) {
    *(int4*)(rowptr + base) = o;
    *(int4*)(cursor + base) = o;
  } else {
    int oo[4] = {o.x, o.y, o.z, o.w};
    for (int i = 0; i < 4; ++i)
      if (base + i < n) { rowptr[base + i] = oo[i]; cursor[base + i] = oo[i]; }
  }
}

// Counting-sort pass 1: partition edges into 49 dst-bucket pair regions.
__global__ __launch_bounds__(256) void partition_kernel(const int* __restrict__ src,
                                                        const int* __restrict__ dst,
                                                        int* __restrict__ bcursor,
                                                        int2* __restrict__ pairs, int E) {
  __shared__ int sS[4096];
  __shared__ int sD[4096];
  __shared__ int hist[NB];
  __shared__ int base[NB];
  int tid = threadIdx.x;
  int base_e = blockIdx.x * 4096;
  int cnt = min(4096, E - base_e);
  if (tid < NB) hist[tid] = 0;
  for (int i = tid * 4; i < cnt; i += 1024) {
    if (i + 3 < cnt) {
      *(int4*)(sS + i) = *(const int4*)(src + base_e + i);
      *(int4*)(sD + i) = *(const int4*)(dst + base_e + i);
    } else {
      for (int k = i; k < cnt; ++k) { sS[k] = src[base_e + k]; sD[k] = dst[base_e + k]; }
    }
  }
  __syncthreads();
  for (int i = tid; i < cnt; i += 256) atomicAdd(&hist[sD[i] >> 11], 1);
  __syncthreads();
  if (tid < NB) {
    base[tid] = atomicAdd(&bcursor[tid], hist[tid]);
    hist[tid] = 0;
  }
  __syncthreads();
  for (int i = tid; i < cnt; i += 256) {
    int d = sD[i];
    int b = d >> 11;
    int off = atomicAdd(&hist[b], 1);
    pairs[base[b] + off] = make_int2(sS[i], d);
  }
}

// Counting-sort pass 2: per-bucket scatter to final CSR positions.
__global__ __launch_bounds__(256) void scatter_csr(const int2* __restrict__ pairs,
                                                   const int* __restrict__ rowptr,
                                                   int* __restrict__ cursor,
                                                   int* __restrict__ csr_src) {
  int b = blockIdx.x % 56;
  int slice = blockIdx.x / 56;
  if (b >= NB) return;
  int start = rowptr[b * 2048];
  int endn = min((b + 1) * 2048, NN);
  int end = rowptr[endn];
  for (int i = start + slice * 256 + threadIdx.x; i < end; i += 8 * 256) {
    int2 p = pairs[i];
    int pos = atomicAdd(&cursor[p.y], 1);
    csr_src[pos] = p.x;
  }
}

// ---------------- merged converts: x -> bf16, WT1/WT2/W2T -> [N][K] bf16 ----
#define NF2B (NN * HH / 4)            // 3,200,000 float4 items
#define NCVW (LL * 16384 + 32768)     // trunk weights + W2T items
__global__ void convert_all(const float* __restrict__ x, unsigned short* __restrict__ x16,
                            const float* __restrict__ cW1, const float* __restrict__ cW2,
                            unsigned short* __restrict__ WT1, unsigned short* __restrict__ WT2,
                            const float* __restrict__ epW2, unsigned short* __restrict__ W2T) {
  int gi = blockIdx.x * 256 + threadIdx.x;
  if (gi < NF2B) {
    float4 v = ((const float4*)x)[gi];
    unsigned short r[4] = {f2bf(v.x), f2bf(v.y), f2bf(v.z), f2bf(v.w)};
    *(uint2*)(x16 + (size_t)gi * 4) = *(uint2*)r;
    return;
  }
  int idx = gi - NF2B;
  if (idx < LL * 16384) {
    int l = idx >> 14, r = idx & 16383, k = r >> 7, n = r & 127;
    WT1[l * 16384 + n * 128 + k] = f2bf(cW1[idx]);
    WT2[l * 16384 + n * 128 + k] = f2bf(cW2[idx]);
  } else if (idx < NCVW) {
    int j = idx - LL * 16384;
    int k = j >> 7, n = j & 127;
    W2T[(size_t)n * 256 + k] = f2bf(epW2[j]);
  }
}

// ---------------- BN-fold of epW1 (runs after all trunk layers) ----------
__global__ __launch_bounds__(256) void ep_w1_prep(
    const float* __restrict__ epW1, const float* __restrict__ epb1,
    const float* __restrict__ bnsum, const float* __restrict__ bnsumsq,
    const float* __restrict__ gamma, const float* __restrict__ beta,
    unsigned short* __restrict__ W1T, float* __restrict__ b1x) {
  __shared__ float red[256];
  int n = blockIdx.x;
  int tid = threadIdx.x;
  const float inv_n = 1.0f / (float)NN;
  int k0 = tid * 4;
  unsigned short w16[4];
  float part = 0.f;
#pragma unroll
  for (int j = 0; j < 4; ++j) {
    int k = k0 + j;
    int c = k & 511;
    float mu = bnsum[c] * inv_n;
    float var = bnsumsq[c] * inv_n - mu * mu;
    float s = rsqrtf(var + 1e-5f) * gamma[c];
    float o = beta[c] - s * mu;
    float w = epW1[(size_t)k * 256 + n];
    w16[j] = f2bf(s * w);
    part += o * w;
  }
  *(uint2*)(W1T + (size_t)n * 1024 + k0) = *(uint2*)w16;
  red[tid] = part;
  __syncthreads();
  for (int st = 128; st >= 1; st >>= 1) {
    if (tid < st) red[tid] += red[tid + st];
    __syncthreads();
  }
  if (tid == 0) b1x[n] = epb1[n] + red[0];
}

// ---------------- fused GIN layer: aggregate (gather -> As LDS) + 2 GEMMs ----
// Phase A: stage B1 -> Bs. Phase B: 16 subgroups x 16 lanes aggregate the
// block's 128 node rows directly into As (BN-affine of prev layer folded;
// g16a intermediate eliminated). Phase C..: the proven barrier-free GEMM
// pipeline (R8 structure). Gather (latency-bound) of one block overlaps
// MFMA of the co-resident block on the same CU.
__global__ __launch_bounds__(256) void layer_fused(
    const unsigned short* __restrict__ h16, int ld,
    const int* __restrict__ rowptr, const int* __restrict__ csr_src,
    const float* __restrict__ ceps_l,
    const float* __restrict__ bnsum_prev, const float* __restrict__ bnsumsq_prev,
    const float* __restrict__ gamma_prev, const float* __restrict__ beta_prev,
    const unsigned short* __restrict__ W1T, const float* __restrict__ b1,
    const unsigned short* __restrict__ W2T, const float* __restrict__ b2,
    float* __restrict__ bnsum, float* __restrict__ bnsumsq,
    unsigned short* __restrict__ C16 /* emb16 slice, row stride 512 */, int M) {
  __shared__ unsigned short As[128 * LDA2];
  __shared__ unsigned short Bs[128 * LDA2];
  const int tid = threadIdx.x;
  const int bm = blockIdx.x * 128;
  const int lane = tid & 63;
  const int wave = tid >> 6;
  const int wr = (wave >> 1) << 6;
  const int wc = (wave & 1) << 6;
  const int ar = tid >> 1;
  const int ah = (tid & 1) << 4;
  const unsigned short* B1row = W1T + (size_t)ar * 128;
  const int mrow = lane & 15;
  const int kq = (lane >> 4) << 3;

  // ---- Phase A: stage full B1 [128][128] into Bs ----
  {
    uint4 bR[8];
#pragma unroll
    for (int i = 0; i < 4; ++i) {
      bR[2 * i]     = *(const uint4*)(B1row + (i << 5) + ah);
      bR[2 * i + 1] = *(const uint4*)(B1row + (i << 5) + ah + 8);
    }
#pragma unroll
    for (int i = 0; i < 4; ++i) {
      *(uint4*)(Bs + ar * LDA2 + (i << 5) + ah)     = bR[2 * i];
      *(uint4*)(Bs + ar * LDA2 + (i << 5) + ah + 8) = bR[2 * i + 1];
    }
  }
  // ---- Phase B: aggregate 128 node rows into As ----
  {
    const int sg = tid >> 4;    // 16 subgroups
    const int li = tid & 15;
    const int c8 = li * 8;
    float eps1 = 1.0f + *ceps_l;
    float scv[8], offv[8];
    if (bnsum_prev) {
      const float inv_n = 1.0f / (float)NN;
#pragma unroll
      for (int k = 0; k < 8; ++k) {
        int c = c8 + k;
        float mu = bnsum_prev[c] * inv_n;
        float var = bnsumsq_prev[c] * inv_n - mu * mu;
        float s = rsqrtf(var + 1e-5f) * gamma_prev[c];
        scv[k] = s;
        offv[k] = beta_prev[c] - s * mu;
      }
    } else {
#pragma unroll
      for (int k = 0; k < 8; ++k) { scv[k] = 1.f; offv[k] = 0.f; }
    }
    for (int it = 0; it < 8; ++it) {
      int nodeLocal = it * 16 + sg;
      int node = bm + nodeLocal;
      if (node >= M) node = M - 1;
      int b0 = rowptr[node], e0 = rowptr[node + 1];
      float acc[8] = {};
      int j = b0;
      for (; j + 4 <= e0; j += 4) {
        uint4 u[4];
#pragma unroll
        for (int t = 0; t < 4; ++t) {
          int s = csr_src[j + t];
          u[t] = *(const uint4*)(h16 + (size_t)s * ld + c8);
        }
#pragma unroll
        for (int t = 0; t < 4; ++t) {
          acc[0] += bl(u[t].x); acc[1] += bh(u[t].x);
          acc[2] += bl(u[t].y); acc[3] += bh(u[t].y);
          acc[4] += bl(u[t].z); acc[5] += bh(u[t].z);
          acc[6] += bl(u[t].w); acc[7] += bh(u[t].w);
        }
      }
      for (; j < e0; ++j) {
        int s = csr_src[j];
        uint4 u = *(const uint4*)(h16 + (size_t)s * ld + c8);
        acc[0] += bl(u.x); acc[1] += bh(u.x);
        acc[2] += bl(u.y); acc[3] += bh(u.y);
        acc[4] += bl(u.z); acc[5] += bh(u.z);
        acc[6] += bl(u.w); acc[7] += bh(u.w);
      }
      uint4 hu = *(const uint4*)(h16 + (size_t)node * ld + c8);
      acc[0] = fmaf(eps1, bl(hu.x), acc[0]); acc[1] = fmaf(eps1, bh(hu.x), acc[1]);
      acc[2] = fmaf(eps1, bl(hu.y), acc[2]); acc[3] = fmaf(eps1, bh(hu.y), acc[3]);
      acc[4] = fmaf(eps1, bl(hu.z), acc[4]); acc[5] = fmaf(eps1, bh(hu.z), acc[5]);
      acc[6] = fmaf(eps1, bl(hu.w), acc[6]); acc[7] = fmaf(eps1, bh(hu.w), acc[7]);
      float degw = (float)(e0 - b0) + eps1;
      unsigned short o[8];
#pragma unroll
      for (int i = 0; i < 8; ++i) o[i] = f2bf(fmaf(scv[i], acc[i], degw * offv[i]));
      *(uint4*)(As + nodeLocal * LDA2 + c8) = *(uint4*)o;
    }
  }
  f32x4 acc[4][4] = {};
  __syncthreads();
  // ---- Phase C: GEMM1, barrier-free K loop ----
#pragma unroll
  for (int ks = 0; ks < 4; ++ks) {
    const int k0 = ks << 5;
    bf16x8 af[4], bfv[4];
#pragma unroll
    for (int t = 0; t < 4; ++t)
      af[t] = *(const bf16x8*)(As + (wr + t * 16 + mrow) * LDA2 + k0 + kq);
#pragma unroll
    for (int t = 0; t < 4; ++t)
      bfv[t] = *(const bf16x8*)(Bs + (wc + t * 16 + mrow) * LDA2 + k0 + kq);
#pragma unroll
    for (int mt = 0; mt < 4; ++mt)
#pragma unroll
      for (int nt = 0; nt < 4; ++nt)
        acc[mt][nt] = __builtin_amdgcn_mfma_f32_16x16x32_bf16(af[mt], bfv[nt], acc[mt][nt], 0, 0, 0);
  }
  uint4 w2[8];
  {
    const unsigned short* B2row = W2T + (size_t)ar * 128;
#pragma unroll
    for (int i = 0; i < 4; ++i) {
      w2[2 * i]     = *(const uint4*)(B2row + (i << 5) + ah);
      w2[2 * i + 1] = *(const uint4*)(B2row + (i << 5) + ah + 8);
    }
  }
  __syncthreads();
  const int crow = (lane >> 4) << 2;
  const int ccol = lane & 15;
#pragma unroll
  for (int nt = 0; nt < 4; ++nt) {
    int c = wc + nt * 16 + ccol;
    float bz = b1[c];
#pragma unroll
    for (int mt = 0; mt < 4; ++mt) {
      int rl = wr + mt * 16 + crow;
#pragma unroll
      for (int i = 0; i < 4; ++i)
        As[(rl + i) * LDA2 + c] = f2bf(fmaxf(acc[mt][nt][i] + bz, 0.f));
    }
  }
#pragma unroll
  for (int i = 0; i < 4; ++i) {
    *(uint4*)(Bs + ar * LDA2 + (i << 5) + ah)     = w2[2 * i];
    *(uint4*)(Bs + ar * LDA2 + (i << 5) + ah + 8) = w2[2 * i + 1];
  }
#pragma unroll
  for (int mt = 0; mt < 4; ++mt)
#pragma unroll
    for (int nt = 0; nt < 4; ++nt)
      acc[mt][nt] = (f32x4){0.f, 0.f, 0.f, 0.f};
  __syncthreads();
#pragma unroll
  for (int ks = 0; ks < 4; ++ks) {
    const int k0 = ks << 5;
    bf16x8 af[4], bfv[4];
#pragma unroll
    for (int t = 0; t < 4; ++t)
      af[t] = *(const bf16x8*)(As + (wr + t * 16 + mrow) * LDA2 + k0 + kq);
#pragma unroll
    for (int t = 0; t < 4; ++t)
      bfv[t] = *(const bf16x8*)(Bs + (wc + t * 16 + mrow) * LDA2 + k0 + kq);
#pragma unroll
    for (int mt = 0; mt < 4; ++mt)
#pragma unroll
      for (int nt = 0; nt < 4; ++nt)
        acc[mt][nt] = __builtin_amdgcn_mfma_f32_16x16x32_bf16(af[mt], bfv[nt], acc[mt][nt], 0, 0, 0);
  }
  // ---- epilogue: bn-sums + z -> Bs (LDS), then vectorized global copy ----
  __syncthreads();  // all waves done reading W2 from Bs
#pragma unroll
  for (int nt = 0; nt < 4; ++nt) {
    int c = wc + nt * 16 + ccol;
    float bz = b2[c];
    float s = 0.f, q = 0.f;
#pragma unroll
    for (int mt = 0; mt < 4; ++mt) {
      int rl = wr + mt * 16 + crow;
      int rbase = bm + rl;
#pragma unroll
      for (int i = 0; i < 4; ++i) {
        float v = fmaxf(acc[mt][nt][i] + bz, 0.f);
        Bs[(rl + i) * LDA2 + c] = f2bf(v);
        if (rbase + i < M) { s += v; q += v * v; }
      }
    }
    s += __shfl_xor(s, 16, 64);
    s += __shfl_xor(s, 32, 64);
    q += __shfl_xor(q, 16, 64);
    q += __shfl_xor(q, 32, 64);
    if (lane < 16) {
      atomicAdd(&bnsum[c], s);
      atomicAdd(&bnsumsq[c], q);
    }
  }
  __syncthreads();
  // copy Bs -> C16: 16 lanes/row x uint4 => 256B contiguous per 4-row instr
#pragma unroll
  for (int p = 0; p < 8; ++p) {
    int r = p * 16 + (tid >> 4);
    int q8 = (tid & 15) * 8;
    if (bm + r < M)
      *(uint4*)(C16 + (size_t)(bm + r) * 512 + q8) =
          *(const uint4*)(Bs + r * LDA2 + q8);
  }
}

// ep fully fused (R7 structure, measured ~107 µs — unchanged).
__global__ __launch_bounds__(512, 4) void ep_fused(
    const unsigned short* __restrict__ emb16, const int* __restrict__ cand,
    const unsigned short* __restrict__ W1T /*[256][1024]*/,
    const float* __restrict__ b1,
    const unsigned short* __restrict__ W2T /*[128][256]*/,
    const float* __restrict__ b2, const float* __restrict__ epW3,
    const float* __restrict__ epb3,
    float* __restrict__ out, int M) {
  __shared__ unsigned short smem[128 * LDC];
  __shared__ float sDotA[128];
  __shared__ float sDotB[128];
  unsigned short* const As0 = smem;
  unsigned short* const As1 = smem + 128 * LDK;
  unsigned short* const Bs0 = smem + 2 * 128 * LDK;
  unsigned short* const Bs1 = smem + 2 * 128 * LDK + 256 * LDK;
  const int tid = threadIdx.x;
  const int bm = blockIdx.x * 128;
  const int lane = tid & 63;
  const int wave = tid >> 6;
  const int wr = (wave >> 2) << 6;   // 2 M-strips of 64
  const int wc = (wave & 3) << 6;    // 4 N-strips of 64
  f32x4 acc[4][4] = {};
  const int ar = tid >> 2;
  const int ah = (tid & 3) << 3;
  int gra = bm + ar; if (gra >= M) gra = M - 1;
  const int node0 = cand[gra];
  const int node1 = cand[NC + gra];
  const int br = tid >> 1;
  const int bh8 = (tid & 1) << 4;
  const unsigned short* Brow = W1T + (size_t)br * 1024 + bh8;
  const unsigned short* Arow0 = emb16 + (size_t)node0 * 512 + ah;
  const unsigned short* Arow1 = emb16 + (size_t)node1 * 512 + ah - 512; // +k*32 for k>=16
  const int mrow = lane & 15;
  const int kq = (lane >> 4) << 3;

  auto ldA = [&](int k) -> uint4 {
    const unsigned short* p = (k < 16) ? Arow0 : Arow1;
    return *(const uint4*)(p + (k << 5));
  };
  auto ldB0v = [&](int k) -> uint4 { return *(const uint4*)(Brow + (k << 5)); };
  auto ldB1v = [&](int k) -> uint4 { return *(const uint4*)(Brow + (k << 5) + 8); };
  auto stTile = [&](unsigned short* Ab, unsigned short* Bb, uint4 a, uint4 x0, uint4 x1) {
    *(uint4*)(Ab + ar * LDK + ah) = a;
    *(uint4*)(Bb + br * LDK + bh8) = x0;
    *(uint4*)(Bb + br * LDK + bh8 + 8) = x1;
  };
  auto mma_step = [&](const unsigned short* A, const unsigned short* B) {
    bf16x8 af[4], bfv[4];
#pragma unroll
    for (int t = 0; t < 4; ++t)
      af[t] = *(const bf16x8*)(A + (wr + t * 16 + mrow) * LDK + kq);
#pragma unroll
    for (int t = 0; t < 4; ++t)
      bfv[t] = *(const bf16x8*)(B + (wc + t * 16 + mrow) * LDK + kq);
#pragma unroll
    for (int mt = 0; mt < 4; ++mt)
#pragma unroll
      for (int nt = 0; nt < 4; ++nt)
        acc[mt][nt] = __builtin_amdgcn_mfma_f32_16x16x32_bf16(af[mt], bfv[nt], acc[mt][nt], 0, 0, 0);
  };

  uint4 aA, aB, b0, b1v;
  {
    uint4 a0 = ldA(0), x0 = ldB0v(0), x1 = ldB1v(0);
    stTile(As0, Bs0, a0, x0, x1);
    aA = ldA(1); b0 = ldB0v(1); b1v = ldB1v(1);
    aB = ldA(2);
  }
  __syncthreads();
  for (int it = 0; it < 16; ++it) {
    const int s0 = 2 * it;
    stTile(As1, Bs1, aA, b0, b1v);
    if (s0 + 3 < 32) aA = ldA(s0 + 3);
    if (s0 + 2 < 32) { b0 = ldB0v(s0 + 2); b1v = ldB1v(s0 + 2); }
    mma_step(As0, Bs0);
    __syncthreads();
    const int s1 = s0 + 1;
    if (s1 < 31) {
      stTile(As0, Bs0, aB, b0, b1v);
      if (s1 + 3 < 32) aB = ldA(s1 + 3);
      if (s1 + 2 < 32) { b0 = ldB0v(s1 + 2); b1v = ldB1v(s1 + 2); }
    }
    mma_step(As1, Bs1);
    __syncthreads();
  }

  const int crow = (lane >> 4) << 2;
  const int ccol = lane & 15;
#pragma unroll
  for (int nt = 0; nt < 4; ++nt) {
    int c = wc + nt * 16 + ccol;
    float bz = b1[c];
#pragma unroll
    for (int mt = 0; mt < 4; ++mt) {
      int rl = wr + mt * 16 + crow;
#pragma unroll
      for (int i = 0; i < 4; ++i)
        smem[(rl + i) * LDC + c] = f2bf(fmaxf(acc[mt][nt][i] + bz, 0.f));
    }
  }
  __syncthreads();
  // GEMM2: [128 x 256] @ W2T^T -> [128 x 128]; A from LDS, B from global (L2-hot 64KB).
  const int wr2 = (wave >> 1) << 5;   // 4 M-strips of 32
  const int wc2 = (wave & 1) << 6;    // 2 N-strips of 64
  f32x4 acc2[2][4] = {};
  for (int ks = 0; ks < 8; ++ks) {
    const int k0 = ks << 5;
    bf16x8 af[2], bfv[4];
#pragma unroll
    for (int t = 0; t < 2; ++t)
      af[t] = *(const bf16x8*)(smem + (wr2 + t * 16 + mrow) * LDC + k0 + kq);
#pragma unroll
    for (int t = 0; t < 4; ++t)
      bfv[t] = *(const bf16x8*)(W2T + (size_t)(wc2 + t * 16 + mrow) * 256 + k0 + kq);
#pragma unroll
    for (int mt = 0; mt < 2; ++mt)
#pragma unroll
      for (int nt = 0; nt < 4; ++nt)
        acc2[mt][nt] = __builtin_amdgcn_mfma_f32_16x16x32_bf16(af[mt], bfv[nt], acc2[mt][nt], 0, 0, 0);
  }
  // epilogue: shfl-reduce the 16 ccol partials per row; one store per row.
  float w3v[4], bz2[4];
#pragma unroll
  for (int nt = 0; nt < 4; ++nt) {
    int c = wc2 + nt * 16 + ccol;
    w3v[nt] = epW3[c];
    bz2[nt] = b2[c];
  }
  float* sBank = (wave & 1) ? sDotB : sDotA;
#pragma unroll
  for (int mt = 0; mt < 2; ++mt) {
#pragma unroll
    for (int i = 0; i < 4; ++i) {
      int rl = wr2 + mt * 16 + crow + i;
      float p = 0.f;
#pragma unroll
      for (int nt = 0; nt < 4; ++nt)
        p = fmaf(fmaxf(acc2[mt][nt][i] + bz2[nt], 0.f), w3v[nt], p);
      p += __shfl_xor(p, 1, 64);
      p += __shfl_xor(p, 2, 64);
      p += __shfl_xor(p, 4, 64);
      p += __shfl_xor(p, 8, 64);
      if ((lane & 15) == 0) sBank[rl] = p;
    }
  }
  __syncthreads();
  if (tid < 128) {
    int r = bm + tid;
    if (r < M) out[r] = 1.f / (1.f + expf(-(sDotA[tid] + sDotB[tid] + epb3[0])));
  }
}

// ---------------- pooling (inline graph bounds, vectorized reads) ----------
__global__ __launch_bounds__(256) void pool_bf16(const unsigned short* __restrict__ emb16,
                                                 const int* __restrict__ batch,
                                                 float* __restrict__ gsum) {
  __shared__ int se[2];
  __shared__ float sRed[512];
  int g = blockIdx.x;
  int chunk = blockIdx.y;
  int tid = threadIdx.x;
  if (tid < 2) {
    int x = g + tid;
    int lo = 0, hi = NN;
    while (lo < hi) {
      int mid = (lo + hi) >> 1;
      if (batch[mid] < x) lo = mid + 1; else hi = mid;
    }
    se[tid] = lo;
  }
  __syncthreads();
  int s = se[0], e = se[1];
  int len = e - s;
  int per = (len + 7) >> 3;
  int r0 = s + chunk * per;
  int r1 = min(r0 + per, e);
  int c8 = (tid & 63) * 8;
  int wgrp = tid >> 6;
  float acc[8] = {};
  for (int r = r0 + wgrp; r < r1; r += 4) {
    uint4 u = *(const uint4*)(emb16 + (size_t)r * 512 + c8);
    acc[0] += bl(u.x); acc[1] += bh(u.x);
    acc[2] += bl(u.y); acc[3] += bh(u.y);
    acc[4] += bl(u.z); acc[5] += bh(u.z);
    acc[6] += bl(u.w); acc[7] += bh(u.w);
  }
  if (wgrp == 0) {
#pragma unroll
    for (int j = 0; j < 8; ++j) sRed[c8 + j] = acc[j];
  }
  __syncthreads();
  for (int w = 1; w < 4; ++w) {
    if (wgrp == w) {
#pragma unroll
      for (int j = 0; j < 8; ++j) sRed[c8 + j] += acc[j];
    }
    __syncthreads();
  }
  if (r0 < r1 && tid < 128) {
#pragma unroll
    for (int j = 0; j < 4; ++j)
      atomicAdd(&gsum[g * 512 + tid * 4 + j], sRed[tid * 4 + j]);
  }
}

// ---------------- fused node classifier (inline bounds + BN affine on mean) --
__global__ __launch_bounds__(256) void nc_fused(
    const float* __restrict__ gsum, const int* __restrict__ batch,
    const float* __restrict__ bnsum, const float* __restrict__ bnsumsq,
    const float* __restrict__ gamma, const float* __restrict__ beta,
    const float* __restrict__ W1, const float* __restrict__ b1,
    const float* __restrict__ W2, const float* __restrict__ b2,
    const float* __restrict__ W3, const float* __restrict__ b3,
    const float* __restrict__ W4, const float* __restrict__ b4,
    float* __restrict__ out) {
  __shared__ float row[512];
  __shared__ float t1[256];
  __shared__ float t2[128];
  __shared__ float t3s[128];
  __shared__ float lg[16];
  __shared__ int se[2];
  int g = blockIdx.x;
  int tid = threadIdx.x;
  if (tid < 2) {
    int x = g + tid;
    int lo = 0, hi = NN;
    while (lo < hi) {
      int mid = (lo + hi) >> 1;
      if (batch[mid] < x) lo = mid + 1; else hi = mid;
    }
    se[tid] = lo;
  }
  __syncthreads();
  float inv = 1.0f / fmaxf((float)(se[1] - se[0]), 1.0f);
  const float inv_n = 1.0f / (float)NN;
#pragma unroll
  for (int h = 0; h < 2; ++h) {
    int c = tid + h * 256;
    float mu = bnsum[c] * inv_n;
    float var = bnsumsq[c] * inv_n - mu * mu;
    float s = rsqrtf(var + 1e-5f) * gamma[c];
    float o = beta[c] - s * mu;
    row[c] = fmaf(gsum[g * 512 + c] * inv, s, o);
  }
  __syncthreads();
  {
    float acc = b1[tid];
#pragma unroll 8
    for (int k = 0; k < 512; ++k) acc = fmaf(row[k], W1[k * 256 + tid], acc);
    t1[tid] = fmaxf(acc, 0.f);
  }
  __syncthreads();
  if (tid < 128) {
    float acc = b2[tid];
#pragma unroll 8
    for (int k = 0; k < 256; ++k) acc = fmaf(t1[k], W2[k * 128 + tid], acc);
    t2[tid] = fmaxf(acc, 0.f);
  }
  __syncthreads();
  if (tid < 128) {
    float acc = b3[tid];
#pragma unroll 8
    for (int k = 0; k < 128; ++k) acc = fmaf(t2[k], W3[k * 128 + tid], acc);
    t3s[tid] = fmaxf(acc, 0.f);
  }
  __syncthreads();
  if (tid < 16) {
    float acc = b4[tid];
#pragma unroll 8
    for (int k = 0; k < 128; ++k) acc = fmaf(t3s[k], W4[k * 16 + tid], acc);
    lg[tid] = acc;
  }
  __syncthreads();
  if (tid < 16) {
    float v = lg[tid];
    float m = v;
    for (int j = 0; j < 16; ++j) m = fmaxf(m, lg[j]);
    float s = 0.f;
    for (int j = 0; j < 16; ++j) s += expf(lg[j] - m);
    out[g * 16 + tid] = v - m - logf(s);
  }
}

// ---------------- launch ----------------
extern "C" void kernel_launch(void* const* d_in, const int* in_sizes, int n_in,
                              void* d_out, int out_size, void* d_ws, size_t ws_size,
                              hipStream_t stream) {
  const float* x = (const float*)d_in[0];
  const int* edge_index = (const int*)d_in[1];
  const int* batch = (const int*)d_in[2];
  const int* cand = (const int*)d_in[3];
  const float* cW1 = (const float*)d_in[4];
  const float* cb1 = (const float*)d_in[5];
  const float* cW2 = (const float*)d_in[6];
  const float* cb2 = (const float*)d_in[7];
  const float* cgamma = (const float*)d_in[8];
  const float* cbeta = (const float*)d_in[9];
  const float* ceps = (const float*)d_in[10];
  const float* ncW1 = (const float*)d_in[11];
  const float* ncb1 = (const float*)d_in[12];
  const float* ncW2 = (const float*)d_in[13];
  const float* ncb2 = (const float*)d_in[14];
  const float* ncW3 = (const float*)d_in[15];
  const float* ncb3 = (const float*)d_in[16];
  const float* ncW4 = (const float*)d_in[17];
  const float* ncb4 = (const float*)d_in[18];
  const float* epW1 = (const float*)d_in[19];
  const float* epb1 = (const float*)d_in[20];
  const float* epW2 = (const float*)d_in[21];
  const float* epb2 = (const float*)d_in[22];
  const float* epW3 = (const float*)d_in[23];
  const float* epb3 = (const float*)d_in[24];

  char* ws = (char*)d_ws;
  size_t off = 0;
  auto alloc = [&](size_t bytes) -> void* {
    off = (off + 255) & ~(size_t)255;
    void* p = ws + off;
    off += bytes;
    return p;
  };
  // zero zone: cnt | bnsum | bnsumsq | gsum
  size_t zz_bytes = (size_t)NN * 4 + 512 * 4 + 512 * 4 + (size_t)GG * 512 * 4;
  char* zz = (char*)alloc(zz_bytes);
  int* cnt = (int*)zz;
  float* bnsum = (float*)(zz + (size_t)NN * 4);
  float* bnsumsq = bnsum + 512;
  float* gsum = bnsumsq + 512;
  int* rowptr = (int*)alloc((size_t)(NN + 1) * 4);
  int* cursor = (int*)alloc((size_t)NN * 4);
  int* csr_src = (int*)alloc((size_t)EE * 4);
  int2* pairs = (int2*)alloc((size_t)EE * 8);
  int* bsum = (int*)alloc(128 * 4);
  int* bcursor = (int*)alloc(64 * 4);
  unsigned short* x16 = (unsigned short*)alloc((size_t)NN * 128 * 2);
  unsigned short* emb16 = (unsigned short*)alloc((size_t)NN * 512 * 2);
  unsigned short* WT1 = (unsigned short*)alloc((size_t)LL * 16384 * 2);
  unsigned short* WT2 = (unsigned short*)alloc((size_t)LL * 16384 * 2);
  unsigned short* W1T = (unsigned short*)alloc((size_t)1024 * 256 * 2);
  unsigned short* W2T = (unsigned short*)alloc((size_t)256 * 128 * 2);
  float* b1x = (float*)alloc(256 * 4);

  const int* esrc = edge_index;
  const int* edst = edge_index + EE;
  const int nblk = (NN + 1023) / 1024;   // 98
  const int nech = (EE + 4095) / 4096;   // 391

  hipMemsetAsync(zz, 0, zz_bytes, stream);
  hist_kernel<<<(EE / 4 + 255) / 256, 256, 0, stream>>>(edst, cnt, EE);
  scan_p1<<<nblk, 256, 0, stream>>>(cnt, bsum, NN);
  scan_p2<<<1, 128, 0, stream>>>(bsum, rowptr, bcursor, nblk, NN);
  scan_p3<<<nblk, 256, 0, stream>>>(cnt, bsum, rowptr, cursor, NN);
  partition_kernel<<<nech, 256, 0, stream>>>(esrc, edst, bcursor, pairs, EE);
  scatter_csr<<<56 * 8, 256, 0, stream>>>(pairs, rowptr, cursor, csr_src);
  convert_all<<<(NF2B + NCVW + 255) / 256, 256, 0, stream>>>(
      x, x16, cW1, cW2, WT1, WT2, epW2, W2T);

  for (int l = 0; l < LL; ++l) {
    const unsigned short* h16 = (l == 0) ? x16 : (emb16 + (size_t)(l - 1) * 128);
    int ld = (l == 0) ? 128 : 512;
    layer_fused<<<(NN + 127) / 128, 256, 0, stream>>>(
        h16, ld, rowptr, csr_src, ceps + l,
        (l == 0) ? nullptr : bnsum + (l - 1) * 128,
        (l == 0) ? nullptr : bnsumsq + (l - 1) * 128,
        (l == 0) ? nullptr : cgamma + (l - 1) * 128,
        (l == 0) ? nullptr : cbeta + (l - 1) * 128,
        WT1 + (size_t)l * 16384, cb1 + l * 128,
        WT2 + (size_t)l * 16384, cb2 + l * 128,
        bnsum + l * 128, bnsumsq + l * 128, emb16 + (size_t)l * 128, NN);
  }
  ep_w1_prep<<<256, 256, 0, stream>>>(epW1, epb1, bnsum, bnsumsq, cgamma, cbeta,
                                      W1T, b1x);

  pool_bf16<<<dim3(GG, 8), 256, 0, stream>>>(emb16, batch, gsum);
  nc_fused<<<GG, 256, 0, stream>>>(gsum, batch, bnsum, bnsumsq, cgamma, cbeta,
                                   ncW1, ncb1, ncW2, ncb2, ncW3, ncb3,
                                   ncW4, ncb4, (float*)d_out);

  ep_fused<<<(NC + 127) / 128, 512, 0, stream>>>(
      emb16, cand, W1T, b1x, W2T, epb2, epW3, epb3,
      (float*)d_out + GG * CCLS, NC);
}

// Round 12
// 1001.914 us; speedup vs baseline: 1.0365x; 1.0365x over previous
//
#include <hip/hip_runtime.h>
#include <math.h>

#define NN 100000
#define EE 1600000
#define GG 64
#define HH 128
#define LL 4
#define CCLS 16
#define NC 100000
#define NB 49    // dst buckets of 2048 nodes
#define LDK 40   // padded LDS row stride (bf16 elems) for 32-wide K tiles
#define LDA2 136 // padded LDS row stride for full-K (128) tiles
#define LDC 260  // padded stride for the fused C1 tile (dword stride 130 ≡ 2 mod 32: ≤2-way banks)

typedef __attribute__((ext_vector_type(8))) short bf16x8;
typedef __attribute__((ext_vector_type(4))) float f32x4;

__device__ __forceinline__ unsigned short f2bf(float x) {
  union { float f; unsigned int u; } v; v.f = x;
  unsigned int r = v.u + 0x7fffu + ((v.u >> 16) & 1u);
  return (unsigned short)(r >> 16);
}
__device__ __forceinline__ float bl(unsigned u) {
  union { unsigned u; float f; } v; v.u = u << 16; return v.f;
}
__device__ __forceinline__ float bh(unsigned u) {
  union { unsigned u; float f; } v; v.u = u & 0xffff0000u; return v.f;
}

// ---------------- CSR build ----------------
__global__ void hist_kernel(const int* __restrict__ dst, int* __restrict__ cnt, int E) {
  int i = (blockIdx.x * 256 + threadIdx.x) * 4;
  if (i + 3 < E) {
    int4 v = *(const int4*)(dst + i);
    atomicAdd(&cnt[v.x], 1);
    atomicAdd(&cnt[v.y], 1);
    atomicAdd(&cnt[v.z], 1);
    atomicAdd(&cnt[v.w], 1);
  } else {
    for (int k = i; k < E; ++k) atomicAdd(&cnt[dst[k]], 1);
  }
}

__global__ __launch_bounds__(256) void scan_p1(const int* __restrict__ cnt,
                                               int* __restrict__ bsum, int n) {
  __shared__ int red[256];
  int tid = threadIdx.x;
  int base = blockIdx.x * 1024 + tid * 4;
  int s = 0;
  if (base + 3 < n) {
    int4 v = *(const int4*)(cnt + base);
    s = v.x + v.y + v.z + v.w;
  } else {
    for (int i = 0; i < 4; ++i) if (base + i < n) s += cnt[base + i];
  }
  red[tid] = s;
  __syncthreads();
  for (int st = 128; st >= 1; st >>= 1) {
    if (tid < st) red[tid] += red[tid + st];
    __syncthreads();
  }
  if (tid == 0) bsum[blockIdx.x] = red[0];
}

__global__ void scan_p2(int* __restrict__ bsum, int* __restrict__ rowptr,
                        int* __restrict__ bcursor, int nb, int n) {
  __shared__ int buf[128];
  int tid = threadIdx.x;
  int v = (tid < nb) ? bsum[tid] : 0;
  buf[tid] = v;
  __syncthreads();
  for (int off = 1; off < 128; off <<= 1) {
    int t = (tid >= off) ? buf[tid - off] : 0;
    __syncthreads();
    buf[tid] += t;
    __syncthreads();
  }
  if (tid < nb) bsum[tid] = buf[tid] - v;
  if (tid == 127) rowptr[n] = buf[127];
  __syncthreads();
  if (tid < NB) bcursor[tid] = bsum[2 * tid];
}

__global__ __launch_bounds__(256) void scan_p3(const int* __restrict__ cnt,
                                               const int* __restrict__ bsum,
                                               int* __restrict__ rowptr,
                                               int* __restrict__ cursor, int n) {
  __shared__ int red[256];
  int tid = threadIdx.x;
  int base = blockIdx.x * 1024 + tid * 4;
  int v[4] = {0, 0, 0, 0};
  if (base + 3 < n) {
    int4 t = *(const int4*)(cnt + base);
    v[0] = t.x; v[1] = t.y; v[2] = t.z; v[3] = t.w;
  } else {
    for (int i = 0; i < 4; ++i) if (base + i < n) v[i] = cnt[base + i];
  }
  int s = v[0] + v[1] + v[2] + v[3];
  red[tid] = s;
  __syncthreads();
  for (int off = 1; off < 256; off <<= 1) {
    int t = (tid >= off) ? red[tid - off] : 0;
    __syncthreads();
    red[tid] += t;
    __syncthreads();
  }
  int run = bsum[blockIdx.x] + red[tid] - s;
  int4 o;
  o.x = run; o.y = run + v[0]; o.z = o.y + v[1]; o.w = o.z + v[2];
  if (base + 3 < n) {
    *(int4*)(rowptr + base) = o;
    *(int4*)(cursor + base) = o;
  } else {
    int oo[4] = {o.x, o.y, o.z, o.w};
    for (int i = 0; i < 4; ++i)
      if (base + i < n) { rowptr[base + i] = oo[i]; cursor[base + i] = oo[i]; }
  }
}

// Counting-sort pass 1: partition edges into 49 dst-bucket pair regions.
__global__ __launch_bounds__(256) void partition_kernel(const int* __restrict__ src,
                                                        const int* __restrict__ dst,
                                                        int* __restrict__ bcursor,
                                                        int2* __restrict__ pairs, int E) {
  __shared__ int sS[4096];
  __shared__ int sD[4096];
  __shared__ int hist[NB];
  __shared__ int base[NB];
  int tid = threadIdx.x;
  int base_e = blockIdx.x * 4096;
  int cnt = min(4096, E - base_e);
  if (tid < NB) hist[tid] = 0;
  for (int i = tid * 4; i < cnt; i += 1024) {
    if (i + 3 < cnt) {
      *(int4*)(sS + i) = *(const int4*)(src + base_e + i);
      *(int4*)(sD + i) = *(const int4*)(dst + base_e + i);
    } else {
      for (int k = i; k < cnt; ++k) { sS[k] = src[base_e + k]; sD[k] = dst[base_e + k]; }
    }
  }
  __syncthreads();
  for (int i = tid; i < cnt; i += 256) atomicAdd(&hist[sD[i] >> 11], 1);
  __syncthreads();
  if (tid < NB) {
    base[tid] = atomicAdd(&bcursor[tid], hist[tid]);
    hist[tid] = 0;
  }
  __syncthreads();
  for (int i = tid; i < cnt; i += 256) {
    int d = sD[i];
    int b = d >> 11;
    int off = atomicAdd(&hist[b], 1);
    pairs[base[b] + off] = make_int2(sS[i], d);
  }
}

// Counting-sort pass 2: per-bucket scatter to final CSR positions.
__global__ __launch_bounds__(256) void scatter_csr(const int2* __restrict__ pairs,
                                                   const int* __restrict__ rowptr,
                                                   int* __restrict__ cursor,
                                                   int* __restrict__ csr_src) {
  int b = blockIdx.x % NB;
  int slice = blockIdx.x / NB;
  int start = rowptr[b * 2048];
  int endn = min((b + 1) * 2048, NN);
  int end = rowptr[endn];
  for (int i = start + slice * 256 + threadIdx.x; i < end; i += 8 * 256) {
    int2 p = pairs[i];
    int pos = atomicAdd(&cursor[p.y], 1);
    csr_src[pos] = p.x;
  }
}

// ---------------- merged converts: x -> bf16, WT1/WT2/W2T -> [N][K] bf16 ----
#define NF2B (NN * HH / 4)            // 3,200,000 float4 items
#define NCVW (LL * 16384 + 32768)     // trunk weights + W2T items
__global__ void convert_all(const float* __restrict__ x, unsigned short* __restrict__ x16,
                            const float* __restrict__ cW1, const float* __restrict__ cW2,
                            unsigned short* __restrict__ WT1, unsigned short* __restrict__ WT2,
                            const float* __restrict__ epW2, unsigned short* __restrict__ W2T) {
  int gi = blockIdx.x * 256 + threadIdx.x;
  if (gi < NF2B) {
    float4 v = ((const float4*)x)[gi];
    unsigned short r[4] = {f2bf(v.x), f2bf(v.y), f2bf(v.z), f2bf(v.w)};
    *(uint2*)(x16 + (size_t)gi * 4) = *(uint2*)r;
    return;
  }
  int idx = gi - NF2B;
  if (idx < LL * 16384) {
    int l = idx >> 14, r = idx & 16383, k = r >> 7, n = r & 127;
    WT1[l * 16384 + n * 128 + k] = f2bf(cW1[idx]);
    WT2[l * 16384 + n * 128 + k] = f2bf(cW2[idx]);
  } else if (idx < NCVW) {
    int j = idx - LL * 16384;
    int k = j >> 7, n = j & 127;
    W2T[(size_t)n * 256 + k] = f2bf(epW2[j]);
  }
}

// ---------------- BN-fold of epW1 (runs after all trunk layers) ----------
__global__ __launch_bounds__(256) void ep_w1_prep(
    const float* __restrict__ epW1, const float* __restrict__ epb1,
    const float* __restrict__ bnsum, const float* __restrict__ bnsumsq,
    const float* __restrict__ gamma, const float* __restrict__ beta,
    unsigned short* __restrict__ W1T, float* __restrict__ b1x) {
  __shared__ float red[256];
  int n = blockIdx.x;
  int tid = threadIdx.x;
  const float inv_n = 1.0f / (float)NN;
  int k0 = tid * 4;
  unsigned short w16[4];
  float part = 0.f;
#pragma unroll
  for (int j = 0; j < 4; ++j) {
    int k = k0 + j;
    int c = k & 511;
    float mu = bnsum[c] * inv_n;
    float var = bnsumsq[c] * inv_n - mu * mu;
    float s = rsqrtf(var + 1e-5f) * gamma[c];
    float o = beta[c] - s * mu;
    float w = epW1[(size_t)k * 256 + n];
    w16[j] = f2bf(s * w);
    part += o * w;
  }
  *(uint2*)(W1T + (size_t)n * 1024 + k0) = *(uint2*)w16;
  red[tid] = part;
  __syncthreads();
  for (int st = 128; st >= 1; st >>= 1) {
    if (tid < st) red[tid] += red[tid + st];
    __syncthreads();
  }
  if (tid == 0) b1x[n] = epb1[n] + red[0];
}

// ---------------- GIN aggregate, v2: 64-VGPR / 8-waves-per-SIMD ----------
__global__ __launch_bounds__(256, 8) void aggregate_bf16(
    const unsigned short* __restrict__ h16, int ld,
    const int* __restrict__ rowptr,
    const int* __restrict__ csr_src,
    const float* __restrict__ ceps_l,
    const float* __restrict__ bnsum_prev,
    const float* __restrict__ bnsumsq_prev,
    const float* __restrict__ gamma_prev,
    const float* __restrict__ beta_prev,
    unsigned short* __restrict__ out, int n) {
  int wave = threadIdx.x >> 6;
  int lane = threadIdx.x & 63;
  int sub = lane >> 4;
  int li = lane & 15;
  int node = blockIdx.x * 16 + wave * 4 + sub;
  if (node >= n) return;
  int c8 = li * 8;
  float acc[8] = {};
  int b = rowptr[node], e = rowptr[node + 1];
  int j = b;
  for (; j + 4 <= e; j += 4) {
    uint4 u[4];
#pragma unroll
    for (int t = 0; t < 4; ++t) {
      int s = csr_src[j + t];
      u[t] = *(const uint4*)(h16 + (size_t)s * ld + c8);
    }
#pragma unroll
    for (int t = 0; t < 4; ++t) {
      acc[0] += bl(u[t].x); acc[1] += bh(u[t].x);
      acc[2] += bl(u[t].y); acc[3] += bh(u[t].y);
      acc[4] += bl(u[t].z); acc[5] += bh(u[t].z);
      acc[6] += bl(u[t].w); acc[7] += bh(u[t].w);
    }
  }
  for (; j < e; ++j) {
    int s = csr_src[j];
    uint4 u = *(const uint4*)(h16 + (size_t)s * ld + c8);
    acc[0] += bl(u.x); acc[1] += bh(u.x);
    acc[2] += bl(u.y); acc[3] += bh(u.y);
    acc[4] += bl(u.z); acc[5] += bh(u.z);
    acc[6] += bl(u.w); acc[7] += bh(u.w);
  }
  // self-term + BN affine of previous layer (computed late: not live in loop)
  float eps1 = 1.0f + *ceps_l;
  uint4 hu = *(const uint4*)(h16 + (size_t)node * ld + c8);
  acc[0] = fmaf(eps1, bl(hu.x), acc[0]); acc[1] = fmaf(eps1, bh(hu.x), acc[1]);
  acc[2] = fmaf(eps1, bl(hu.y), acc[2]); acc[3] = fmaf(eps1, bh(hu.y), acc[3]);
  acc[4] = fmaf(eps1, bl(hu.z), acc[4]); acc[5] = fmaf(eps1, bh(hu.z), acc[5]);
  acc[6] = fmaf(eps1, bl(hu.w), acc[6]); acc[7] = fmaf(eps1, bh(hu.w), acc[7]);
  float degw = (float)(e - b) + eps1;
  unsigned short o[8];
  if (bnsum_prev) {
    const float inv_n = 1.0f / (float)NN;
#pragma unroll
    for (int k = 0; k < 8; ++k) {
      int c = c8 + k;
      float mu = bnsum_prev[c] * inv_n;
      float var = bnsumsq_prev[c] * inv_n - mu * mu;
      float s = rsqrtf(var + 1e-5f) * gamma_prev[c];
      float off = beta_prev[c] - s * mu;
      o[k] = f2bf(fmaf(s, acc[k], degw * off));
    }
  } else {
#pragma unroll
    for (int k = 0; k < 8; ++k) o[k] = f2bf(acc[k]);
  }
  *(uint4*)(out + (size_t)node * 128 + c8) = *(uint4*)o;
}

// ---------------- fused trunk layer (full-B stage, barrier-free K loops) ----
// Writes RAW z into the emb16 slice via LDS-staged vectorized copy.
__global__ __launch_bounds__(256) void trunk_fused(
    const unsigned short* __restrict__ A16,
    const unsigned short* __restrict__ W1T, const float* __restrict__ b1,
    const unsigned short* __restrict__ W2T, const float* __restrict__ b2,
    float* __restrict__ bnsum, float* __restrict__ bnsumsq,
    unsigned short* __restrict__ C16 /* emb16 slice, row stride 512 */, int M) {
  __shared__ unsigned short As[128 * LDA2];
  __shared__ unsigned short Bs[128 * LDA2];
  const int tid = threadIdx.x;
  const int bm = blockIdx.x * 128;
  const int lane = tid & 63;
  const int wave = tid >> 6;
  const int wr = (wave >> 1) << 6;
  const int wc = (wave & 1) << 6;
  const int ar = tid >> 1;
  const int ah = (tid & 1) << 4;
  int gra = bm + ar; if (gra >= M) gra = M - 1;
  const unsigned short* Arow = A16 + (size_t)gra * 128;
  const unsigned short* B1row = W1T + (size_t)ar * 128;
  const int mrow = lane & 15;
  const int kq = (lane >> 4) << 3;

  {
    uint4 aR[8], bR[8];
#pragma unroll
    for (int i = 0; i < 4; ++i) {
      aR[2 * i]     = *(const uint4*)(Arow + (i << 5) + ah);
      aR[2 * i + 1] = *(const uint4*)(Arow + (i << 5) + ah + 8);
      bR[2 * i]     = *(const uint4*)(B1row + (i << 5) + ah);
      bR[2 * i + 1] = *(const uint4*)(B1row + (i << 5) + ah + 8);
    }
#pragma unroll
    for (int i = 0; i < 4; ++i) {
      *(uint4*)(As + ar * LDA2 + (i << 5) + ah)     = aR[2 * i];
      *(uint4*)(As + ar * LDA2 + (i << 5) + ah + 8) = aR[2 * i + 1];
      *(uint4*)(Bs + ar * LDA2 + (i << 5) + ah)     = bR[2 * i];
      *(uint4*)(Bs + ar * LDA2 + (i << 5) + ah + 8) = bR[2 * i + 1];
    }
  }
  f32x4 acc[4][4] = {};
  __syncthreads();
#pragma unroll
  for (int ks = 0; ks < 4; ++ks) {
    const int k0 = ks << 5;
    bf16x8 af[4], bfv[4];
#pragma unroll
    for (int t = 0; t < 4; ++t)
      af[t] = *(const bf16x8*)(As + (wr + t * 16 + mrow) * LDA2 + k0 + kq);
#pragma unroll
    for (int t = 0; t < 4; ++t)
      bfv[t] = *(const bf16x8*)(Bs + (wc + t * 16 + mrow) * LDA2 + k0 + kq);
#pragma unroll
    for (int mt = 0; mt < 4; ++mt)
#pragma unroll
      for (int nt = 0; nt < 4; ++nt)
        acc[mt][nt] = __builtin_amdgcn_mfma_f32_16x16x32_bf16(af[mt], bfv[nt], acc[mt][nt], 0, 0, 0);
  }
  uint4 w2[8];
  {
    const unsigned short* B2row = W2T + (size_t)ar * 128;
#pragma unroll
    for (int i = 0; i < 4; ++i) {
      w2[2 * i]     = *(const uint4*)(B2row + (i << 5) + ah);
      w2[2 * i + 1] = *(const uint4*)(B2row + (i << 5) + ah + 8);
    }
  }
  __syncthreads();
  const int crow = (lane >> 4) << 2;
  const int ccol = lane & 15;
#pragma unroll
  for (int nt = 0; nt < 4; ++nt) {
    int c = wc + nt * 16 + ccol;
    float bz = b1[c];
#pragma unroll
    for (int mt = 0; mt < 4; ++mt) {
      int rl = wr + mt * 16 + crow;
#pragma unroll
      for (int i = 0; i < 4; ++i)
        As[(rl + i) * LDA2 + c] = f2bf(fmaxf(acc[mt][nt][i] + bz, 0.f));
    }
  }
#pragma unroll
  for (int i = 0; i < 4; ++i) {
    *(uint4*)(Bs + ar * LDA2 + (i << 5) + ah)     = w2[2 * i];
    *(uint4*)(Bs + ar * LDA2 + (i << 5) + ah + 8) = w2[2 * i + 1];
  }
#pragma unroll
  for (int mt = 0; mt < 4; ++mt)
#pragma unroll
    for (int nt = 0; nt < 4; ++nt)
      acc[mt][nt] = (f32x4){0.f, 0.f, 0.f, 0.f};
  __syncthreads();
#pragma unroll
  for (int ks = 0; ks < 4; ++ks) {
    const int k0 = ks << 5;
    bf16x8 af[4], bfv[4];
#pragma unroll
    for (int t = 0; t < 4; ++t)
      af[t] = *(const bf16x8*)(As + (wr + t * 16 + mrow) * LDA2 + k0 + kq);
#pragma unroll
    for (int t = 0; t < 4; ++t)
      bfv[t] = *(const bf16x8*)(Bs + (wc + t * 16 + mrow) * LDA2 + k0 + kq);
#pragma unroll
    for (int mt = 0; mt < 4; ++mt)
#pragma unroll
      for (int nt = 0; nt < 4; ++nt)
        acc[mt][nt] = __builtin_amdgcn_mfma_f32_16x16x32_bf16(af[mt], bfv[nt], acc[mt][nt], 0, 0, 0);
  }
  // ---- epilogue: bn-sums + z -> Bs (LDS), then vectorized global copy ----
  __syncthreads();  // all waves done reading W2 from Bs
#pragma unroll
  for (int nt = 0; nt < 4; ++nt) {
    int c = wc + nt * 16 + ccol;
    float bz = b2[c];
    float s = 0.f, q = 0.f;
#pragma unroll
    for (int mt = 0; mt < 4; ++mt) {
      int rl = wr + mt * 16 + crow;
      int rbase = bm + rl;
#pragma unroll
      for (int i = 0; i < 4; ++i) {
        float v = fmaxf(acc[mt][nt][i] + bz, 0.f);
        Bs[(rl + i) * LDA2 + c] = f2bf(v);
        if (rbase + i < M) { s += v; q += v * v; }
      }
    }
    s += __shfl_xor(s, 16, 64);
    s += __shfl_xor(s, 32, 64);
    q += __shfl_xor(q, 16, 64);
    q += __shfl_xor(q, 32, 64);
    if (lane < 16) {
      atomicAdd(&bnsum[c], s);
      atomicAdd(&bnsumsq[c], q);
    }
  }
  __syncthreads();
  // copy Bs -> C16: 16 lanes/row x uint4 => 256B contiguous per 4-row instr
#pragma unroll
  for (int p = 0; p < 8; ++p) {
    int r = p * 16 + (tid >> 4);
    int q8 = (tid & 15) * 8;
    if (bm + r < M)
      *(uint4*)(C16 + (size_t)(bm + r) * 512 + q8) =
          *(const uint4*)(Bs + r * LDA2 + q8);
  }
}

// ep fully fused (R7 structure, measured ~107 µs — unchanged).
__global__ __launch_bounds__(512, 4) void ep_fused(
    const unsigned short* __restrict__ emb16, const int* __restrict__ cand,
    const unsigned short* __restrict__ W1T /*[256][1024]*/,
    const float* __restrict__ b1,
    const unsigned short* __restrict__ W2T /*[128][256]*/,
    const float* __restrict__ b2, const float* __restrict__ epW3,
    const float* __restrict__ epb3,
    float* __restrict__ out, int M) {
  __shared__ unsigned short smem[128 * LDC];
  __shared__ float sDotA[128];
  __shared__ float sDotB[128];
  unsigned short* const As0 = smem;
  unsigned short* const As1 = smem + 128 * LDK;
  unsigned short* const Bs0 = smem + 2 * 128 * LDK;
  unsigned short* const Bs1 = smem + 2 * 128 * LDK + 256 * LDK;
  const int tid = threadIdx.x;
  const int bm = blockIdx.x * 128;
  const int lane = tid & 63;
  const int wave = tid >> 6;
  const int wr = (wave >> 2) << 6;   // 2 M-strips of 64
  const int wc = (wave & 3) << 6;    // 4 N-strips of 64
  f32x4 acc[4][4] = {};
  const int ar = tid >> 2;
  const int ah = (tid & 3) << 3;
  int gra = bm + ar; if (gra >= M) gra = M - 1;
  const int node0 = cand[gra];
  const int node1 = cand[NC + gra];
  const int br = tid >> 1;
  const int bh8 = (tid & 1) << 4;
  const unsigned short* Brow = W1T + (size_t)br * 1024 + bh8;
  const unsigned short* Arow0 = emb16 + (size_t)node0 * 512 + ah;
  const unsigned short* Arow1 = emb16 + (size_t)node1 * 512 + ah - 512; // +k*32 for k>=16
  const int mrow = lane & 15;
  const int kq = (lane >> 4) << 3;

  auto ldA = [&](int k) -> uint4 {
    const unsigned short* p = (k < 16) ? Arow0 : Arow1;
    return *(const uint4*)(p + (k << 5));
  };
  auto ldB0v = [&](int k) -> uint4 { return *(const uint4*)(Brow + (k << 5)); };
  auto ldB1v = [&](int k) -> uint4 { return *(const uint4*)(Brow + (k << 5) + 8); };
  auto stTile = [&](unsigned short* Ab, unsigned short* Bb, uint4 a, uint4 x0, uint4 x1) {
    *(uint4*)(Ab + ar * LDK + ah) = a;
    *(uint4*)(Bb + br * LDK + bh8) = x0;
    *(uint4*)(Bb + br * LDK + bh8 + 8) = x1;
  };
  auto mma_step = [&](const unsigned short* A, const unsigned short* B) {
    bf16x8 af[4], bfv[4];
#pragma unroll
    for (int t = 0; t < 4; ++t)
      af[t] = *(const bf16x8*)(A + (wr + t * 16 + mrow) * LDK + kq);
#pragma unroll
    for (int t = 0; t < 4; ++t)
      bfv[t] = *(const bf16x8*)(B + (wc + t * 16 + mrow) * LDK + kq);
#pragma unroll
    for (int mt = 0; mt < 4; ++mt)
#pragma unroll
      for (int nt = 0; nt < 4; ++nt)
        acc[mt][nt] = __builtin_amdgcn_mfma_f32_16x16x32_bf16(af[mt], bfv[nt], acc[mt][nt], 0, 0, 0);
  };

  uint4 aA, aB, b0, b1v;
  {
    uint4 a0 = ldA(0), x0 = ldB0v(0), x1 = ldB1v(0);
    stTile(As0, Bs0, a0, x0, x1);
    aA = ldA(1); b0 = ldB0v(1); b1v = ldB1v(1);
    aB = ldA(2);
  }
  __syncthreads();
  for (int it = 0; it < 16; ++it) {
    const int s0 = 2 * it;
    stTile(As1, Bs1, aA, b0, b1v);
    if (s0 + 3 < 32) aA = ldA(s0 + 3);
    if (s0 + 2 < 32) { b0 = ldB0v(s0 + 2); b1v = ldB1v(s0 + 2); }
    mma_step(As0, Bs0);
    __syncthreads();
    const int s1 = s0 + 1;
    if (s1 < 31) {
      stTile(As0, Bs0, aB, b0, b1v);
      if (s1 + 3 < 32) aB = ldA(s1 + 3);
      if (s1 + 2 < 32) { b0 = ldB0v(s1 + 2); b1v = ldB1v(s1 + 2); }
    }
    mma_step(As1, Bs1);
    __syncthreads();
  }

  const int crow = (lane >> 4) << 2;
  const int ccol = lane & 15;
#pragma unroll
  for (int nt = 0; nt < 4; ++nt) {
    int c = wc + nt * 16 + ccol;
    float bz = b1[c];
#pragma unroll
    for (int mt = 0; mt < 4; ++mt) {
      int rl = wr + mt * 16 + crow;
#pragma unroll
      for (int i = 0; i < 4; ++i)
        smem[(rl + i) * LDC + c] = f2bf(fmaxf(acc[mt][nt][i] + bz, 0.f));
    }
  }
  __syncthreads();
  // GEMM2: [128 x 256] @ W2T^T -> [128 x 128]; A from LDS, B from global (L2-hot 64KB).
  const int wr2 = (wave >> 1) << 5;   // 4 M-strips of 32
  const int wc2 = (wave & 1) << 6;    // 2 N-strips of 64
  f32x4 acc2[2][4] = {};
  for (int ks = 0; ks < 8; ++ks) {
    const int k0 = ks << 5;
    bf16x8 af[2], bfv[4];
#pragma unroll
    for (int t = 0; t < 2; ++t)
      af[t] = *(const bf16x8*)(smem + (wr2 + t * 16 + mrow) * LDC + k0 + kq);
#pragma unroll
    for (int t = 0; t < 4; ++t)
      bfv[t] = *(const bf16x8*)(W2T + (size_t)(wc2 + t * 16 + mrow) * 256 + k0 + kq);
#pragma unroll
    for (int mt = 0; mt < 2; ++mt)
#pragma unroll
      for (int nt = 0; nt < 4; ++nt)
        acc2[mt][nt] = __builtin_amdgcn_mfma_f32_16x16x32_bf16(af[mt], bfv[nt], acc2[mt][nt], 0, 0, 0);
  }
  // epilogue: shfl-reduce the 16 ccol partials per row; one store per row.
  float w3v[4], bz2[4];
#pragma unroll
  for (int nt = 0; nt < 4; ++nt) {
    int c = wc2 + nt * 16 + ccol;
    w3v[nt] = epW3[c];
    bz2[nt] = b2[c];
  }
  float* sBank = (wave & 1) ? sDotB : sDotA;
#pragma unroll
  for (int mt = 0; mt < 2; ++mt) {
#pragma unroll
    for (int i = 0; i < 4; ++i) {
      int rl = wr2 + mt * 16 + crow + i;
      float p = 0.f;
#pragma unroll
      for (int nt = 0; nt < 4; ++nt)
        p = fmaf(fmaxf(acc2[mt][nt][i] + bz2[nt], 0.f), w3v[nt], p);
      p += __shfl_xor(p, 1, 64);
      p += __shfl_xor(p, 2, 64);
      p += __shfl_xor(p, 4, 64);
      p += __shfl_xor(p, 8, 64);
      if ((lane & 15) == 0) sBank[rl] = p;
    }
  }
  __syncthreads();
  if (tid < 128) {
    int r = bm + tid;
    if (r < M) out[r] = 1.f / (1.f + expf(-(sDotA[tid] + sDotB[tid] + epb3[0])));
  }
}

// ---------------- pooling (inline graph bounds, vectorized reads) ----------
__global__ __launch_bounds__(256) void pool_bf16(const unsigned short* __restrict__ emb16,
                                                 const int* __restrict__ batch,
                                                 float* __restrict__ gsum) {
  __shared__ int se[2];
  __shared__ float sRed[512];
  int g = blockIdx.x;
  int chunk = blockIdx.y;
  int tid = threadIdx.x;
  if (tid < 2) {
    int x = g + tid;
    int lo = 0, hi = NN;
    while (lo < hi) {
      int mid = (lo + hi) >> 1;
      if (batch[mid] < x) lo = mid + 1; else hi = mid;
    }
    se[tid] = lo;
  }
  __syncthreads();
  int s = se[0], e = se[1];
  int len = e - s;
  int per = (len + 7) >> 3;
  int r0 = s + chunk * per;
  int r1 = min(r0 + per, e);
  int c8 = (tid & 63) * 8;
  int wgrp = tid >> 6;
  float acc[8] = {};
  for (int r = r0 + wgrp; r < r1; r += 4) {
    uint4 u = *(const uint4*)(emb16 + (size_t)r * 512 + c8);
    acc[0] += bl(u.x); acc[1] += bh(u.x);
    acc[2] += bl(u.y); acc[3] += bh(u.y);
    acc[4] += bl(u.z); acc[5] += bh(u.z);
    acc[6] += bl(u.w); acc[7] += bh(u.w);
  }
  if (wgrp == 0) {
#pragma unroll
    for (int j = 0; j < 8; ++j) sRed[c8 + j] = acc[j];
  }
  __syncthreads();
  for (int w = 1; w < 4; ++w) {
    if (wgrp == w) {
#pragma unroll
      for (int j = 0; j < 8; ++j) sRed[c8 + j] += acc[j];
    }
    __syncthreads();
  }
  if (r0 < r1 && tid < 128) {
#pragma unroll
    for (int j = 0; j < 4; ++j)
      atomicAdd(&gsum[g * 512 + tid * 4 + j], sRed[tid * 4 + j]);
  }
}

// ---------------- fused node classifier (inline bounds + BN affine on mean) --
__global__ __launch_bounds__(256) void nc_fused(
    const float* __restrict__ gsum, const int* __restrict__ batch,
    const float* __restrict__ bnsum, const float* __restrict__ bnsumsq,
    const float* __restrict__ gamma, const float* __restrict__ beta,
    const float* __restrict__ W1, const float* __restrict__ b1,
    const float* __restrict__ W2, const float* __restrict__ b2,
    const float* __restrict__ W3, const float* __restrict__ b3,
    const float* __restrict__ W4, const float* __restrict__ b4,
    float* __restrict__ out) {
  __shared__ float row[512];
  __shared__ float t1[256];
  __shared__ float t2[128];
  __shared__ float t3s[128];
  __shared__ float lg[16];
  __shared__ int se[2];
  int g = blockIdx.x;
  int tid = threadIdx.x;
  if (tid < 2) {
    int x = g + tid;
    int lo = 0, hi = NN;
    while (lo < hi) {
      int mid = (lo + hi) >> 1;
      if (batch[mid] < x) lo = mid + 1; else hi = mid;
    }
    se[tid] = lo;
  }
  __syncthreads();
  float inv = 1.0f / fmaxf((float)(se[1] - se[0]), 1.0f);
  const float inv_n = 1.0f / (float)NN;
#pragma unroll
  for (int h = 0; h < 2; ++h) {
    int c = tid + h * 256;
    float mu = bnsum[c] * inv_n;
    float var = bnsumsq[c] * inv_n - mu * mu;
    float s = rsqrtf(var + 1e-5f) * gamma[c];
    float o = beta[c] - s * mu;
    row[c] = fmaf(gsum[g * 512 + c] * inv, s, o);
  }
  __syncthreads();
  {
    float acc = b1[tid];
#pragma unroll 8
    for (int k = 0; k < 512; ++k) acc = fmaf(row[k], W1[k * 256 + tid], acc);
    t1[tid] = fmaxf(acc, 0.f);
  }
  __syncthreads();
  if (tid < 128) {
    float acc = b2[tid];
#pragma unroll 8
    for (int k = 0; k < 256; ++k) acc = fmaf(t1[k], W2[k * 128 + tid], acc);
    t2[tid] = fmaxf(acc, 0.f);
  }
  __syncthreads();
  if (tid < 128) {
    float acc = b3[tid];
#pragma unroll 8
    for (int k = 0; k < 128; ++k) acc = fmaf(t2[k], W3[k * 128 + tid], acc);
    t3s[tid] = fmaxf(acc, 0.f);
  }
  __syncthreads();
  if (tid < 16) {
    float acc = b4[tid];
#pragma unroll 8
    for (int k = 0; k < 128; ++k) acc = fmaf(t3s[k], W4[k * 16 + tid], acc);
    lg[tid] = acc;
  }
  __syncthreads();
  if (tid < 16) {
    float v = lg[tid];
    float m = v;
    for (int j = 0; j < 16; ++j) m = fmaxf(m, lg[j]);
    float s = 0.f;
    for (int j = 0; j < 16; ++j) s += expf(lg[j] - m);
    out[g * 16 + tid] = v - m - logf(s);
  }
}

// ---------------- launch ----------------
extern "C" void kernel_launch(void* const* d_in, const int* in_sizes, int n_in,
                              void* d_out, int out_size, void* d_ws, size_t ws_size,
                              hipStream_t stream) {
  const float* x = (const float*)d_in[0];
  const int* edge_index = (const int*)d_in[1];
  const int* batch = (const int*)d_in[2];
  const int* cand = (const int*)d_in[3];
  const float* cW1 = (const float*)d_in[4];
  const float* cb1 = (const float*)d_in[5];
  const float* cW2 = (const float*)d_in[6];
  const float* cb2 = (const float*)d_in[7];
  const float* cgamma = (const float*)d_in[8];
  const float* cbeta = (const float*)d_in[9];
  const float* ceps = (const float*)d_in[10];
  const float* ncW1 = (const float*)d_in[11];
  const float* ncb1 = (const float*)d_in[12];
  const float* ncW2 = (const float*)d_in[13];
  const float* ncb2 = (const float*)d_in[14];
  const float* ncW3 = (const float*)d_in[15];
  const float* ncb3 = (const float*)d_in[16];
  const float* ncW4 = (const float*)d_in[17];
  const float* ncb4 = (const float*)d_in[18];
  const float* epW1 = (const float*)d_in[19];
  const float* epb1 = (const float*)d_in[20];
  const float* epW2 = (const float*)d_in[21];
  const float* epb2 = (const float*)d_in[22];
  const float* epW3 = (const float*)d_in[23];
  const float* epb3 = (const float*)d_in[24];

  char* ws = (char*)d_ws;
  size_t off = 0;
  auto alloc = [&](size_t bytes) -> void* {
    off = (off + 255) & ~(size_t)255;
    void* p = ws + off;
    off += bytes;
    return p;
  };
  // zero zone: cnt | bnsum | bnsumsq | gsum
  size_t zz_bytes = (size_t)NN * 4 + 512 * 4 + 512 * 4 + (size_t)GG * 512 * 4;
  char* zz = (char*)alloc(zz_bytes);
  int* cnt = (int*)zz;
  float* bnsum = (float*)(zz + (size_t)NN * 4);
  float* bnsumsq = bnsum + 512;
  float* gsum = bnsumsq + 512;
  int* rowptr = (int*)alloc((size_t)(NN + 1) * 4);
  int* cursor = (int*)alloc((size_t)NN * 4);
  int* csr_src = (int*)alloc((size_t)EE * 4);
  int2* pairs = (int2*)alloc((size_t)EE * 8);
  int* bsum = (int*)alloc(128 * 4);
  int* bcursor = (int*)alloc(64 * 4);
  unsigned short* x16 = (unsigned short*)alloc((size_t)NN * 128 * 2);
  unsigned short* g16a = (unsigned short*)alloc((size_t)NN * 128 * 2);
  unsigned short* emb16 = (unsigned short*)alloc((size_t)NN * 512 * 2);
  unsigned short* WT1 = (unsigned short*)alloc((size_t)LL * 16384 * 2);
  unsigned short* WT2 = (unsigned short*)alloc((size_t)LL * 16384 * 2);
  unsigned short* W1T = (unsigned short*)alloc((size_t)1024 * 256 * 2);
  unsigned short* W2T = (unsigned short*)alloc((size_t)256 * 128 * 2);
  float* b1x = (float*)alloc(256 * 4);

  const int* esrc = edge_index;
  const int* edst = edge_index + EE;
  const int nblk = (NN + 1023) / 1024;   // 98
  const int nech = (EE + 4095) / 4096;   // 391

  hipMemsetAsync(zz, 0, zz_bytes, stream);
  hist_kernel<<<(EE / 4 + 255) / 256, 256, 0, stream>>>(edst, cnt, EE);
  scan_p1<<<nblk, 256, 0, stream>>>(cnt, bsum, NN);
  scan_p2<<<1, 128, 0, stream>>>(bsum, rowptr, bcursor, nblk, NN);
  scan_p3<<<nblk, 256, 0, stream>>>(cnt, bsum, rowptr, cursor, NN);
  partition_kernel<<<nech, 256, 0, stream>>>(esrc, edst, bcursor, pairs, EE);
  scatter_csr<<<NB * 8, 256, 0, stream>>>(pairs, rowptr, cursor, csr_src);
  convert_all<<<(NF2B + NCVW + 255) / 256, 256, 0, stream>>>(
      x, x16, cW1, cW2, WT1, WT2, epW2, W2T);

  for (int l = 0; l < LL; ++l) {
    const unsigned short* h16 = (l == 0) ? x16 : (emb16 + (size_t)(l - 1) * 128);
    int ld = (l == 0) ? 128 : 512;
    aggregate_bf16<<<(NN + 15) / 16, 256, 0, stream>>>(
        h16, ld, rowptr, csr_src, ceps + l,
        (l == 0) ? nullptr : bnsum + (l - 1) * 128,
        (l == 0) ? nullptr : bnsumsq + (l - 1) * 128,
        (l == 0) ? nullptr : cgamma + (l - 1) * 128,
        (l == 0) ? nullptr : cbeta + (l - 1) * 128,
        g16a, NN);
    trunk_fused<<<(NN + 127) / 128, 256, 0, stream>>>(
        g16a, WT1 + (size_t)l * 16384, cb1 + l * 128,
        WT2 + (size_t)l * 16384, cb2 + l * 128,
        bnsum + l * 128, bnsumsq + l * 128, emb16 + (size_t)l * 128, NN);
  }
  ep_w1_prep<<<256, 256, 0, stream>>>(epW1, epb1, bnsum, bnsumsq, cgamma, cbeta,
                                      W1T, b1x);

  pool_bf16<<<dim3(GG, 8), 256, 0, stream>>>(emb16, batch, gsum);
  nc_fused<<<GG, 256, 0, stream>>>(gsum, batch, bnsum, bnsumsq, cgamma, cbeta,
                                   ncW1, ncb1, ncW2, ncb2, ncW3, ncb3,
                                   ncW4, ncb4, (float*)d_out);

  ep_fused<<<(NC + 127) / 128, 512, 0, stream>>>(
      emb16, cand, W1T, b1x, W2T, epb2, epW3, epb3,
      (float*)d_out + GG * CCLS, NC);
}

// Round 13
// 910.219 us; speedup vs baseline: 1.1409x; 1.1007x over previous
//
#include <hip/hip_runtime.h>
#include <math.h>

#define NN 100000
#define EE 1600000
#define GG 64
#define HH 128
#define LL 4
#define CCLS 16
#define NC 100000
#define NB2 391  // dst buckets of 256 nodes
#define SCAP 6144 // LDS reorder capacity (avg bucket ~4092, +32 sigma)
#define LDK 40   // padded LDS row stride (bf16 elems) for 32-wide K tiles
#define LDA2 136 // padded LDS row stride for full-K (128) tiles
#define LDC 260  // padded stride for the fused C1 tile (dword stride 130 ≡ 2 mod 32: ≤2-way banks)

typedef __attribute__((ext_vector_type(8))) short bf16x8;
typedef __attribute__((ext_vector_type(4))) float f32x4;

__device__ __forceinline__ unsigned short f2bf(float x) {
  union { float f; unsigned int u; } v; v.f = x;
  unsigned int r = v.u + 0x7fffu + ((v.u >> 16) & 1u);
  return (unsigned short)(r >> 16);
}
__device__ __forceinline__ float bl(unsigned u) {
  union { unsigned u; float f; } v; v.u = u << 16; return v.f;
}
__device__ __forceinline__ float bh(unsigned u) {
  union { unsigned u; float f; } v; v.u = u & 0xffff0000u; return v.f;
}

// ---------------- CSR build ----------------
__global__ void hist_kernel(const int* __restrict__ dst, int* __restrict__ cnt, int E) {
  int i = (blockIdx.x * 256 + threadIdx.x) * 4;
  if (i + 3 < E) {
    int4 v = *(const int4*)(dst + i);
    atomicAdd(&cnt[v.x], 1);
    atomicAdd(&cnt[v.y], 1);
    atomicAdd(&cnt[v.z], 1);
    atomicAdd(&cnt[v.w], 1);
  } else {
    for (int k = i; k < E; ++k) atomicAdd(&cnt[dst[k]], 1);
  }
}

__global__ __launch_bounds__(256) void scan_p1(const int* __restrict__ cnt,
                                               int* __restrict__ bsum, int n) {
  __shared__ int red[256];
  int tid = threadIdx.x;
  int base = blockIdx.x * 1024 + tid * 4;
  int s = 0;
  if (base + 3 < n) {
    int4 v = *(const int4*)(cnt + base);
    s = v.x + v.y + v.z + v.w;
  } else {
    for (int i = 0; i < 4; ++i) if (base + i < n) s += cnt[base + i];
  }
  red[tid] = s;
  __syncthreads();
  for (int st = 128; st >= 1; st >>= 1) {
    if (tid < st) red[tid] += red[tid + st];
    __syncthreads();
  }
  if (tid == 0) bsum[blockIdx.x] = red[0];
}

__global__ void scan_p2(int* __restrict__ bsum, int* __restrict__ rowptr, int nb, int n) {
  __shared__ int buf[128];
  int tid = threadIdx.x;
  int v = (tid < nb) ? bsum[tid] : 0;
  buf[tid] = v;
  __syncthreads();
  for (int off = 1; off < 128; off <<= 1) {
    int t = (tid >= off) ? buf[tid - off] : 0;
    __syncthreads();
    buf[tid] += t;
    __syncthreads();
  }
  if (tid < nb) bsum[tid] = buf[tid] - v;
  if (tid == 127) rowptr[n] = buf[127];
}

__global__ __launch_bounds__(256) void scan_p3(const int* __restrict__ cnt,
                                               const int* __restrict__ bsum,
                                               int* __restrict__ rowptr, int n) {
  __shared__ int red[256];
  int tid = threadIdx.x;
  int base = blockIdx.x * 1024 + tid * 4;
  int v[4] = {0, 0, 0, 0};
  if (base + 3 < n) {
    int4 t = *(const int4*)(cnt + base);
    v[0] = t.x; v[1] = t.y; v[2] = t.z; v[3] = t.w;
  } else {
    for (int i = 0; i < 4; ++i) if (base + i < n) v[i] = cnt[base + i];
  }
  int s = v[0] + v[1] + v[2] + v[3];
  red[tid] = s;
  __syncthreads();
  for (int off = 1; off < 256; off <<= 1) {
    int t = (tid >= off) ? red[tid - off] : 0;
    __syncthreads();
    red[tid] += t;
    __syncthreads();
  }
  int run = bsum[blockIdx.x] + red[tid] - s;
  int4 o;
  o.x = run; o.y = run + v[0]; o.z = o.y + v[1]; o.w = o.z + v[2];
  if (base + 3 < n) {
    *(int4*)(rowptr + base) = o;
  } else {
    int oo[4] = {o.x, o.y, o.z, o.w};
    for (int i = 0; i < 4; ++i)
      if (base + i < n) rowptr[base + i] = oo[i];
  }
}

// bucket write-cursors for partition: start of each 256-node bucket region
__global__ void bcursor_init(const int* __restrict__ rowptr, int* __restrict__ bcursor) {
  int b = blockIdx.x * 256 + threadIdx.x;
  if (b < NB2) bcursor[b] = rowptr[b * 256];
}

// Counting-sort pass 1: partition edges into 391 dst-bucket pair regions.
__global__ __launch_bounds__(256) void partition_kernel(const int* __restrict__ src,
                                                        const int* __restrict__ dst,
                                                        int* __restrict__ bcursor,
                                                        int2* __restrict__ pairs, int E) {
  __shared__ int sS[4096];
  __shared__ int sD[4096];
  __shared__ int hist[NB2 + 1];
  __shared__ int base[NB2 + 1];
  int tid = threadIdx.x;
  int base_e = blockIdx.x * 4096;
  int cnt = min(4096, E - base_e);
  for (int h = tid; h < NB2; h += 256) hist[h] = 0;
  for (int i = tid * 4; i < cnt; i += 1024) {
    if (i + 3 < cnt) {
      *(int4*)(sS + i) = *(const int4*)(src + base_e + i);
      *(int4*)(sD + i) = *(const int4*)(dst + base_e + i);
    } else {
      for (int k = i; k < cnt; ++k) { sS[k] = src[base_e + k]; sD[k] = dst[base_e + k]; }
    }
  }
  __syncthreads();
  for (int i = tid; i < cnt; i += 256) atomicAdd(&hist[sD[i] >> 8], 1);
  __syncthreads();
  for (int h = tid; h < NB2; h += 256) {
    base[h] = atomicAdd(&bcursor[h], hist[h]);
    hist[h] = 0;
  }
  __syncthreads();
  for (int i = tid; i < cnt; i += 256) {
    int d = sD[i];
    int b = d >> 8;
    int off = atomicAdd(&hist[b], 1);
    pairs[base[b] + off] = make_int2(sS[i], d);
  }
}

// Counting-sort pass 2: per-bucket LDS reorder, fully coalesced csr writes.
// Local offsets come FREE from rowptr (lofs[i] = rowptr[n0+i]-pstart), so a
// single pass over pairs suffices. Replaces the global atomic scatter whose
// random 4B stores cost 99.6 MB HBM writes (16x amplification).
__global__ __launch_bounds__(256) void scatter_sort(const int2* __restrict__ pairs,
                                                    const int* __restrict__ rowptr,
                                                    int* __restrict__ csr_src) {
  __shared__ int lofs[256];
  __shared__ int sbuf[SCAP];
  int b = blockIdx.x;
  int tid = threadIdx.x;
  int n0 = b * 256;
  int nodes = min(256, NN - n0);
  int pstart = rowptr[n0];
  int L = rowptr[n0 + nodes] - pstart;
  if (tid < nodes) lofs[tid] = rowptr[n0 + tid] - pstart;
  __syncthreads();
  if (L <= SCAP) {
    for (int i = tid; i < L; i += 256) {
      int2 p = pairs[pstart + i];
      int pos = atomicAdd(&lofs[p.y - n0], 1);
      sbuf[pos] = p.x;
    }
    __syncthreads();
    for (int i = tid; i < L; i += 256) csr_src[pstart + i] = sbuf[i];
  } else {
    // fallback (never hit for near-uniform edges): direct global scatter
    for (int i = tid; i < L; i += 256) {
      int2 p = pairs[pstart + i];
      int pos = atomicAdd(&lofs[p.y - n0], 1);
      csr_src[pstart + pos] = p.x;
    }
  }
}

// ---------------- merged converts: x -> bf16, WT1/WT2/W2T -> [N][K] bf16 ----
#define NF2B (NN * HH / 4)            // 3,200,000 float4 items
#define NCVW (LL * 16384 + 32768)     // trunk weights + W2T items
__global__ void convert_all(const float* __restrict__ x, unsigned short* __restrict__ x16,
                            const float* __restrict__ cW1, const float* __restrict__ cW2,
                            unsigned short* __restrict__ WT1, unsigned short* __restrict__ WT2,
                            const float* __restrict__ epW2, unsigned short* __restrict__ W2T) {
  int gi = blockIdx.x * 256 + threadIdx.x;
  if (gi < NF2B) {
    float4 v = ((const float4*)x)[gi];
    unsigned short r[4] = {f2bf(v.x), f2bf(v.y), f2bf(v.z), f2bf(v.w)};
    *(uint2*)(x16 + (size_t)gi * 4) = *(uint2*)r;
    return;
  }
  int idx = gi - NF2B;
  if (idx < LL * 16384) {
    int l = idx >> 14, r = idx & 16383, k = r >> 7, n = r & 127;
    WT1[l * 16384 + n * 128 + k] = f2bf(cW1[idx]);
    WT2[l * 16384 + n * 128 + k] = f2bf(cW2[idx]);
  } else if (idx < NCVW) {
    int j = idx - LL * 16384;
    int k = j >> 7, n = j & 127;
    W2T[(size_t)n * 256 + k] = f2bf(epW2[j]);
  }
}

// ---------------- BN-fold of epW1 (runs after all trunk layers) ----------
__global__ __launch_bounds__(256) void ep_w1_prep(
    const float* __restrict__ epW1, const float* __restrict__ epb1,
    const float* __restrict__ bnsum, const float* __restrict__ bnsumsq,
    const float* __restrict__ gamma, const float* __restrict__ beta,
    unsigned short* __restrict__ W1T, float* __restrict__ b1x) {
  __shared__ float red[256];
  int n = blockIdx.x;
  int tid = threadIdx.x;
  const float inv_n = 1.0f / (float)NN;
  int k0 = tid * 4;
  unsigned short w16[4];
  float part = 0.f;
#pragma unroll
  for (int j = 0; j < 4; ++j) {
    int k = k0 + j;
    int c = k & 511;
    float mu = bnsum[c] * inv_n;
    float var = bnsumsq[c] * inv_n - mu * mu;
    float s = rsqrtf(var + 1e-5f) * gamma[c];
    float o = beta[c] - s * mu;
    float w = epW1[(size_t)k * 256 + n];
    w16[j] = f2bf(s * w);
    part += o * w;
  }
  *(uint2*)(W1T + (size_t)n * 1024 + k0) = *(uint2*)w16;
  red[tid] = part;
  __syncthreads();
  for (int st = 128; st >= 1; st >>= 1) {
    if (tid < st) red[tid] += red[tid + st];
    __syncthreads();
  }
  if (tid == 0) b1x[n] = epb1[n] + red[0];
}

// ---------------- GIN aggregate, v2: 64-VGPR / 8-waves-per-SIMD ----------
__global__ __launch_bounds__(256, 8) void aggregate_bf16(
    const unsigned short* __restrict__ h16, int ld,
    const int* __restrict__ rowptr,
    const int* __restrict__ csr_src,
    const float* __restrict__ ceps_l,
    const float* __restrict__ bnsum_prev,
    const float* __restrict__ bnsumsq_prev,
    const float* __restrict__ gamma_prev,
    const float* __restrict__ beta_prev,
    unsigned short* __restrict__ out, int n) {
  int wave = threadIdx.x >> 6;
  int lane = threadIdx.x & 63;
  int sub = lane >> 4;
  int li = lane & 15;
  int node = blockIdx.x * 16 + wave * 4 + sub;
  if (node >= n) return;
  int c8 = li * 8;
  float acc[8] = {};
  int b = rowptr[node], e = rowptr[node + 1];
  int j = b;
  for (; j + 4 <= e; j += 4) {
    uint4 u[4];
#pragma unroll
    for (int t = 0; t < 4; ++t) {
      int s = csr_src[j + t];
      u[t] = *(const uint4*)(h16 + (size_t)s * ld + c8);
    }
#pragma unroll
    for (int t = 0; t < 4; ++t) {
      acc[0] += bl(u[t].x); acc[1] += bh(u[t].x);
      acc[2] += bl(u[t].y); acc[3] += bh(u[t].y);
      acc[4] += bl(u[t].z); acc[5] += bh(u[t].z);
      acc[6] += bl(u[t].w); acc[7] += bh(u[t].w);
    }
  }
  for (; j < e; ++j) {
    int s = csr_src[j];
    uint4 u = *(const uint4*)(h16 + (size_t)s * ld + c8);
    acc[0] += bl(u.x); acc[1] += bh(u.x);
    acc[2] += bl(u.y); acc[3] += bh(u.y);
    acc[4] += bl(u.z); acc[5] += bh(u.z);
    acc[6] += bl(u.w); acc[7] += bh(u.w);
  }
  // self-term + BN affine of previous layer (computed late: not live in loop)
  float eps1 = 1.0f + *ceps_l;
  uint4 hu = *(const uint4*)(h16 + (size_t)node * ld + c8);
  acc[0] = fmaf(eps1, bl(hu.x), acc[0]); acc[1] = fmaf(eps1, bh(hu.x), acc[1]);
  acc[2] = fmaf(eps1, bl(hu.y), acc[2]); acc[3] = fmaf(eps1, bh(hu.y), acc[3]);
  acc[4] = fmaf(eps1, bl(hu.z), acc[4]); acc[5] = fmaf(eps1, bh(hu.z), acc[5]);
  acc[6] = fmaf(eps1, bl(hu.w), acc[6]); acc[7] = fmaf(eps1, bh(hu.w), acc[7]);
  float degw = (float)(e - b) + eps1;
  unsigned short o[8];
  if (bnsum_prev) {
    const float inv_n = 1.0f / (float)NN;
#pragma unroll
    for (int k = 0; k < 8; ++k) {
      int c = c8 + k;
      float mu = bnsum_prev[c] * inv_n;
      float var = bnsumsq_prev[c] * inv_n - mu * mu;
      float s = rsqrtf(var + 1e-5f) * gamma_prev[c];
      float off = beta_prev[c] - s * mu;
      o[k] = f2bf(fmaf(s, acc[k], degw * off));
    }
  } else {
#pragma unroll
    for (int k = 0; k < 8; ++k) o[k] = f2bf(acc[k]);
  }
  *(uint4*)(out + (size_t)node * 128 + c8) = *(uint4*)o;
}

// ---------------- fused trunk layer (full-B stage, barrier-free K loops) ----
// Writes RAW z into the emb16 slice via LDS-staged vectorized copy.
__global__ __launch_bounds__(256) void trunk_fused(
    const unsigned short* __restrict__ A16,
    const unsigned short* __restrict__ W1T, const float* __restrict__ b1,
    const unsigned short* __restrict__ W2T, const float* __restrict__ b2,
    float* __restrict__ bnsum, float* __restrict__ bnsumsq,
    unsigned short* __restrict__ C16 /* emb16 slice, row stride 512 */, int M) {
  __shared__ unsigned short As[128 * LDA2];
  __shared__ unsigned short Bs[128 * LDA2];
  const int tid = threadIdx.x;
  const int bm = blockIdx.x * 128;
  const int lane = tid & 63;
  const int wave = tid >> 6;
  const int wr = (wave >> 1) << 6;
  const int wc = (wave & 1) << 6;
  const int ar = tid >> 1;
  const int ah = (tid & 1) << 4;
  int gra = bm + ar; if (gra >= M) gra = M - 1;
  const unsigned short* Arow = A16 + (size_t)gra * 128;
  const unsigned short* B1row = W1T + (size_t)ar * 128;
  const int mrow = lane & 15;
  const int kq = (lane >> 4) << 3;

  {
    uint4 aR[8], bR[8];
#pragma unroll
    for (int i = 0; i < 4; ++i) {
      aR[2 * i]     = *(const uint4*)(Arow + (i << 5) + ah);
      aR[2 * i + 1] = *(const uint4*)(Arow + (i << 5) + ah + 8);
      bR[2 * i]     = *(const uint4*)(B1row + (i << 5) + ah);
      bR[2 * i + 1] = *(const uint4*)(B1row + (i << 5) + ah + 8);
    }
#pragma unroll
    for (int i = 0; i < 4; ++i) {
      *(uint4*)(As + ar * LDA2 + (i << 5) + ah)     = aR[2 * i];
      *(uint4*)(As + ar * LDA2 + (i << 5) + ah + 8) = aR[2 * i + 1];
      *(uint4*)(Bs + ar * LDA2 + (i << 5) + ah)     = bR[2 * i];
      *(uint4*)(Bs + ar * LDA2 + (i << 5) + ah + 8) = bR[2 * i + 1];
    }
  }
  f32x4 acc[4][4] = {};
  __syncthreads();
#pragma unroll
  for (int ks = 0; ks < 4; ++ks) {
    const int k0 = ks << 5;
    bf16x8 af[4], bfv[4];
#pragma unroll
    for (int t = 0; t < 4; ++t)
      af[t] = *(const bf16x8*)(As + (wr + t * 16 + mrow) * LDA2 + k0 + kq);
#pragma unroll
    for (int t = 0; t < 4; ++t)
      bfv[t] = *(const bf16x8*)(Bs + (wc + t * 16 + mrow) * LDA2 + k0 + kq);
#pragma unroll
    for (int mt = 0; mt < 4; ++mt)
#pragma unroll
      for (int nt = 0; nt < 4; ++nt)
        acc[mt][nt] = __builtin_amdgcn_mfma_f32_16x16x32_bf16(af[mt], bfv[nt], acc[mt][nt], 0, 0, 0);
  }
  uint4 w2[8];
  {
    const unsigned short* B2row = W2T + (size_t)ar * 128;
#pragma unroll
    for (int i = 0; i < 4; ++i) {
      w2[2 * i]     = *(const uint4*)(B2row + (i << 5) + ah);
      w2[2 * i + 1] = *(const uint4*)(B2row + (i << 5) + ah + 8);
    }
  }
  __syncthreads();
  const int crow = (lane >> 4) << 2;
  const int ccol = lane & 15;
#pragma unroll
  for (int nt = 0; nt < 4; ++nt) {
    int c = wc + nt * 16 + ccol;
    float bz = b1[c];
#pragma unroll
    for (int mt = 0; mt < 4; ++mt) {
      int rl = wr + mt * 16 + crow;
#pragma unroll
      for (int i = 0; i < 4; ++i)
        As[(rl + i) * LDA2 + c] = f2bf(fmaxf(acc[mt][nt][i] + bz, 0.f));
    }
  }
#pragma unroll
  for (int i = 0; i < 4; ++i) {
    *(uint4*)(Bs + ar * LDA2 + (i << 5) + ah)     = w2[2 * i];
    *(uint4*)(Bs + ar * LDA2 + (i << 5) + ah + 8) = w2[2 * i + 1];
  }
#pragma unroll
  for (int mt = 0; mt < 4; ++mt)
#pragma unroll
    for (int nt = 0; nt < 4; ++nt)
      acc[mt][nt] = (f32x4){0.f, 0.f, 0.f, 0.f};
  __syncthreads();
#pragma unroll
  for (int ks = 0; ks < 4; ++ks) {
    const int k0 = ks << 5;
    bf16x8 af[4], bfv[4];
#pragma unroll
    for (int t = 0; t < 4; ++t)
      af[t] = *(const bf16x8*)(As + (wr + t * 16 + mrow) * LDA2 + k0 + kq);
#pragma unroll
    for (int t = 0; t < 4; ++t)
      bfv[t] = *(const bf16x8*)(Bs + (wc + t * 16 + mrow) * LDA2 + k0 + kq);
#pragma unroll
    for (int mt = 0; mt < 4; ++mt)
#pragma unroll
      for (int nt = 0; nt < 4; ++nt)
        acc[mt][nt] = __builtin_amdgcn_mfma_f32_16x16x32_bf16(af[mt], bfv[nt], acc[mt][nt], 0, 0, 0);
  }
  // ---- epilogue: bn-sums + z -> Bs (LDS), then vectorized global copy ----
  __syncthreads();  // all waves done reading W2 from Bs
#pragma unroll
  for (int nt = 0; nt < 4; ++nt) {
    int c = wc + nt * 16 + ccol;
    float bz = b2[c];
    float s = 0.f, q = 0.f;
#pragma unroll
    for (int mt = 0; mt < 4; ++mt) {
      int rl = wr + mt * 16 + crow;
      int rbase = bm + rl;
#pragma unroll
      for (int i = 0; i < 4; ++i) {
        float v = fmaxf(acc[mt][nt][i] + bz, 0.f);
        Bs[(rl + i) * LDA2 + c] = f2bf(v);
        if (rbase + i < M) { s += v; q += v * v; }
      }
    }
    s += __shfl_xor(s, 16, 64);
    s += __shfl_xor(s, 32, 64);
    q += __shfl_xor(q, 16, 64);
    q += __shfl_xor(q, 32, 64);
    if (lane < 16) {
      atomicAdd(&bnsum[c], s);
      atomicAdd(&bnsumsq[c], q);
    }
  }
  __syncthreads();
  // copy Bs -> C16: 16 lanes/row x uint4 => 256B contiguous per 4-row instr
#pragma unroll
  for (int p = 0; p < 8; ++p) {
    int r = p * 16 + (tid >> 4);
    int q8 = (tid & 15) * 8;
    if (bm + r < M)
      *(uint4*)(C16 + (size_t)(bm + r) * 512 + q8) =
          *(const uint4*)(Bs + r * LDA2 + q8);
  }
}

// ep fully fused (R7 structure, measured ~107 µs — unchanged).
__global__ __launch_bounds__(512, 4) void ep_fused(
    const unsigned short* __restrict__ emb16, const int* __restrict__ cand,
    const unsigned short* __restrict__ W1T /*[256][1024]*/,
    const float* __restrict__ b1,
    const unsigned short* __restrict__ W2T /*[128][256]*/,
    const float* __restrict__ b2, const float* __restrict__ epW3,
    const float* __restrict__ epb3,
    float* __restrict__ out, int M) {
  __shared__ unsigned short smem[128 * LDC];
  __shared__ float sDotA[128];
  __shared__ float sDotB[128];
  unsigned short* const As0 = smem;
  unsigned short* const As1 = smem + 128 * LDK;
  unsigned short* const Bs0 = smem + 2 * 128 * LDK;
  unsigned short* const Bs1 = smem + 2 * 128 * LDK + 256 * LDK;
  const int tid = threadIdx.x;
  const int bm = blockIdx.x * 128;
  const int lane = tid & 63;
  const int wave = tid >> 6;
  const int wr = (wave >> 2) << 6;   // 2 M-strips of 64
  const int wc = (wave & 3) << 6;    // 4 N-strips of 64
  f32x4 acc[4][4] = {};
  const int ar = tid >> 2;
  const int ah = (tid & 3) << 3;
  int gra = bm + ar; if (gra >= M) gra = M - 1;
  const int node0 = cand[gra];
  const int node1 = cand[NC + gra];
  const int br = tid >> 1;
  const int bh8 = (tid & 1) << 4;
  const unsigned short* Brow = W1T + (size_t)br * 1024 + bh8;
  const unsigned short* Arow0 = emb16 + (size_t)node0 * 512 + ah;
  const unsigned short* Arow1 = emb16 + (size_t)node1 * 512 + ah - 512; // +k*32 for k>=16
  const int mrow = lane & 15;
  const int kq = (lane >> 4) << 3;

  auto ldA = [&](int k) -> uint4 {
    const unsigned short* p = (k < 16) ? Arow0 : Arow1;
    return *(const uint4*)(p + (k << 5));
  };
  auto ldB0v = [&](int k) -> uint4 { return *(const uint4*)(Brow + (k << 5)); };
  auto ldB1v = [&](int k) -> uint4 { return *(const uint4*)(Brow + (k << 5) + 8); };
  auto stTile = [&](unsigned short* Ab, unsigned short* Bb, uint4 a, uint4 x0, uint4 x1) {
    *(uint4*)(Ab + ar * LDK + ah) = a;
    *(uint4*)(Bb + br * LDK + bh8) = x0;
    *(uint4*)(Bb + br * LDK + bh8 + 8) = x1;
  };
  auto mma_step = [&](const unsigned short* A, const unsigned short* B) {
    bf16x8 af[4], bfv[4];
#pragma unroll
    for (int t = 0; t < 4; ++t)
      af[t] = *(const bf16x8*)(A + (wr + t * 16 + mrow) * LDK + kq);
#pragma unroll
    for (int t = 0; t < 4; ++t)
      bfv[t] = *(const bf16x8*)(B + (wc + t * 16 + mrow) * LDK + kq);
#pragma unroll
    for (int mt = 0; mt < 4; ++mt)
#pragma unroll
      for (int nt = 0; nt < 4; ++nt)
        acc[mt][nt] = __builtin_amdgcn_mfma_f32_16x16x32_bf16(af[mt], bfv[nt], acc[mt][nt], 0, 0, 0);
  };

  uint4 aA, aB, b0, b1v;
  {
    uint4 a0 = ldA(0), x0 = ldB0v(0), x1 = ldB1v(0);
    stTile(As0, Bs0, a0, x0, x1);
    aA = ldA(1); b0 = ldB0v(1); b1v = ldB1v(1);
    aB = ldA(2);
  }
  __syncthreads();
  for (int it = 0; it < 16; ++it) {
    const int s0 = 2 * it;
    stTile(As1, Bs1, aA, b0, b1v);
    if (s0 + 3 < 32) aA = ldA(s0 + 3);
    if (s0 + 2 < 32) { b0 = ldB0v(s0 + 2); b1v = ldB1v(s0 + 2); }
    mma_step(As0, Bs0);
    __syncthreads();
    const int s1 = s0 + 1;
    if (s1 < 31) {
      stTile(As0, Bs0, aB, b0, b1v);
      if (s1 + 3 < 32) aB = ldA(s1 + 3);
      if (s1 + 2 < 32) { b0 = ldB0v(s1 + 2); b1v = ldB1v(s1 + 2); }
    }
    mma_step(As1, Bs1);
    __syncthreads();
  }

  const int crow = (lane >> 4) << 2;
  const int ccol = lane & 15;
#pragma unroll
  for (int nt = 0; nt < 4; ++nt) {
    int c = wc + nt * 16 + ccol;
    float bz = b1[c];
#pragma unroll
    for (int mt = 0; mt < 4; ++mt) {
      int rl = wr + mt * 16 + crow;
#pragma unroll
      for (int i = 0; i < 4; ++i)
        smem[(rl + i) * LDC + c] = f2bf(fmaxf(acc[mt][nt][i] + bz, 0.f));
    }
  }
  __syncthreads();
  // GEMM2: [128 x 256] @ W2T^T -> [128 x 128]; A from LDS, B from global (L2-hot 64KB).
  const int wr2 = (wave >> 1) << 5;   // 4 M-strips of 32
  const int wc2 = (wave & 1) << 6;    // 2 N-strips of 64
  f32x4 acc2[2][4] = {};
  for (int ks = 0; ks < 8; ++ks) {
    const int k0 = ks << 5;
    bf16x8 af[2], bfv[4];
#pragma unroll
    for (int t = 0; t < 2; ++t)
      af[t] = *(const bf16x8*)(smem + (wr2 + t * 16 + mrow) * LDC + k0 + kq);
#pragma unroll
    for (int t = 0; t < 4; ++t)
      bfv[t] = *(const bf16x8*)(W2T + (size_t)(wc2 + t * 16 + mrow) * 256 + k0 + kq);
#pragma unroll
    for (int mt = 0; mt < 2; ++mt)
#pragma unroll
      for (int nt = 0; nt < 4; ++nt)
        acc2[mt][nt] = __builtin_amdgcn_mfma_f32_16x16x32_bf16(af[mt], bfv[nt], acc2[mt][nt], 0, 0, 0);
  }
  // epilogue: shfl-reduce the 16 ccol partials per row; one store per row.
  float w3v[4], bz2[4];
#pragma unroll
  for (int nt = 0; nt < 4; ++nt) {
    int c = wc2 + nt * 16 + ccol;
    w3v[nt] = epW3[c];
    bz2[nt] = b2[c];
  }
  float* sBank = (wave & 1) ? sDotB : sDotA;
#pragma unroll
  for (int mt = 0; mt < 2; ++mt) {
#pragma unroll
    for (int i = 0; i < 4; ++i) {
      int rl = wr2 + mt * 16 + crow + i;
      float p = 0.f;
#pragma unroll
      for (int nt = 0; nt < 4; ++nt)
        p = fmaf(fmaxf(acc2[mt][nt][i] + bz2[nt], 0.f), w3v[nt], p);
      p += __shfl_xor(p, 1, 64);
      p += __shfl_xor(p, 2, 64);
      p += __shfl_xor(p, 4, 64);
      p += __shfl_xor(p, 8, 64);
      if ((lane & 15) == 0) sBank[rl] = p;
    }
  }
  __syncthreads();
  if (tid < 128) {
    int r = bm + tid;
    if (r < M) out[r] = 1.f / (1.f + expf(-(sDotA[tid] + sDotB[tid] + epb3[0])));
  }
}

// ---------------- pooling (inline graph bounds, vectorized reads) ----------
__global__ __launch_bounds__(256) void pool_bf16(const unsigned short* __restrict__ emb16,
                                                 const int* __restrict__ batch,
                                                 float* __restrict__ gsum) {
  __shared__ int se[2];
  __shared__ float sRed[512];
  int g = blockIdx.x;
  int chunk = blockIdx.y;
  int tid = threadIdx.x;
  if (tid < 2) {
    int x = g + tid;
    int lo = 0, hi = NN;
    while (lo < hi) {
      int mid = (lo + hi) >> 1;
      if (batch[mid] < x) lo = mid + 1; else hi = mid;
    }
    se[tid] = lo;
  }
  __syncthreads();
  int s = se[0], e = se[1];
  int len = e - s;
  int per = (len + 7) >> 3;
  int r0 = s + chunk * per;
  int r1 = min(r0 + per, e);
  int c8 = (tid & 63) * 8;
  int wgrp = tid >> 6;
  float acc[8] = {};
  for (int r = r0 + wgrp; r < r1; r += 4) {
    uint4 u = *(const uint4*)(emb16 + (size_t)r * 512 + c8);
    acc[0] += bl(u.x); acc[1] += bh(u.x);
    acc[2] += bl(u.y); acc[3] += bh(u.y);
    acc[4] += bl(u.z); acc[5] += bh(u.z);
    acc[6] += bl(u.w); acc[7] += bh(u.w);
  }
  if (wgrp == 0) {
#pragma unroll
    for (int j = 0; j < 8; ++j) sRed[c8 + j] = acc[j];
  }
  __syncthreads();
  for (int w = 1; w < 4; ++w) {
    if (wgrp == w) {
#pragma unroll
      for (int j = 0; j < 8; ++j) sRed[c8 + j] += acc[j];
    }
    __syncthreads();
  }
  if (r0 < r1 && tid < 128) {
#pragma unroll
    for (int j = 0; j < 4; ++j)
      atomicAdd(&gsum[g * 512 + tid * 4 + j], sRed[tid * 4 + j]);
  }
}

// ---------------- fused node classifier (inline bounds + BN affine on mean) --
__global__ __launch_bounds__(256) void nc_fused(
    const float* __restrict__ gsum, const int* __restrict__ batch,
    const float* __restrict__ bnsum, const float* __restrict__ bnsumsq,
    const float* __restrict__ gamma, const float* __restrict__ beta,
    const float* __restrict__ W1, const float* __restrict__ b1,
    const float* __restrict__ W2, const float* __restrict__ b2,
    const float* __restrict__ W3, const float* __restrict__ b3,
    const float* __restrict__ W4, const float* __restrict__ b4,
    float* __restrict__ out) {
  __shared__ float row[512];
  __shared__ float t1[256];
  __shared__ float t2[128];
  __shared__ float t3s[128];
  __shared__ float lg[16];
  __shared__ int se[2];
  int g = blockIdx.x;
  int tid = threadIdx.x;
  if (tid < 2) {
    int x = g + tid;
    int lo = 0, hi = NN;
    while (lo < hi) {
      int mid = (lo + hi) >> 1;
      if (batch[mid] < x) lo = mid + 1; else hi = mid;
    }
    se[tid] = lo;
  }
  __syncthreads();
  float inv = 1.0f / fmaxf((float)(se[1] - se[0]), 1.0f);
  const float inv_n = 1.0f / (float)NN;
#pragma unroll
  for (int h = 0; h < 2; ++h) {
    int c = tid + h * 256;
    float mu = bnsum[c] * inv_n;
    float var = bnsumsq[c] * inv_n - mu * mu;
    float s = rsqrtf(var + 1e-5f) * gamma[c];
    float o = beta[c] - s * mu;
    row[c] = fmaf(gsum[g * 512 + c] * inv, s, o);
  }
  __syncthreads();
  {
    float acc = b1[tid];
#pragma unroll 8
    for (int k = 0; k < 512; ++k) acc = fmaf(row[k], W1[k * 256 + tid], acc);
    t1[tid] = fmaxf(acc, 0.f);
  }
  __syncthreads();
  if (tid < 128) {
    float acc = b2[tid];
#pragma unroll 8
    for (int k = 0; k < 256; ++k) acc = fmaf(t1[k], W2[k * 128 + tid], acc);
    t2[tid] = fmaxf(acc, 0.f);
  }
  __syncthreads();
  if (tid < 128) {
    float acc = b3[tid];
#pragma unroll 8
    for (int k = 0; k < 128; ++k) acc = fmaf(t2[k], W3[k * 128 + tid], acc);
    t3s[tid] = fmaxf(acc, 0.f);
  }
  __syncthreads();
  if (tid < 16) {
    float acc = b4[tid];
#pragma unroll 8
    for (int k = 0; k < 128; ++k) acc = fmaf(t3s[k], W4[k * 16 + tid], acc);
    lg[tid] = acc;
  }
  __syncthreads();
  if (tid < 16) {
    float v = lg[tid];
    float m = v;
    for (int j = 0; j < 16; ++j) m = fmaxf(m, lg[j]);
    float s = 0.f;
    for (int j = 0; j < 16; ++j) s += expf(lg[j] - m);
    out[g * 16 + tid] = v - m - logf(s);
  }
}

// ---------------- launch ----------------
extern "C" void kernel_launch(void* const* d_in, const int* in_sizes, int n_in,
                              void* d_out, int out_size, void* d_ws, size_t ws_size,
                              hipStream_t stream) {
  const float* x = (const float*)d_in[0];
  const int* edge_index = (const int*)d_in[1];
  const int* batch = (const int*)d_in[2];
  const int* cand = (const int*)d_in[3];
  const float* cW1 = (const float*)d_in[4];
  const float* cb1 = (const float*)d_in[5];
  const float* cW2 = (const float*)d_in[6];
  const float* cb2 = (const float*)d_in[7];
  const float* cgamma = (const float*)d_in[8];
  const float* cbeta = (const float*)d_in[9];
  const float* ceps = (const float*)d_in[10];
  const float* ncW1 = (const float*)d_in[11];
  const float* ncb1 = (const float*)d_in[12];
  const float* ncW2 = (const float*)d_in[13];
  const float* ncb2 = (const float*)d_in[14];
  const float* ncW3 = (const float*)d_in[15];
  const float* ncb3 = (const float*)d_in[16];
  const float* ncW4 = (const float*)d_in[17];
  const float* ncb4 = (const float*)d_in[18];
  const float* epW1 = (const float*)d_in[19];
  const float* epb1 = (const float*)d_in[20];
  const float* epW2 = (const float*)d_in[21];
  const float* epb2 = (const float*)d_in[22];
  const float* epW3 = (const float*)d_in[23];
  const float* epb3 = (const float*)d_in[24];

  char* ws = (char*)d_ws;
  size_t off = 0;
  auto alloc = [&](size_t bytes) -> void* {
    off = (off + 255) & ~(size_t)255;
    void* p = ws + off;
    off += bytes;
    return p;
  };
  // zero zone: cnt | bnsum | bnsumsq | gsum
  size_t zz_bytes = (size_t)NN * 4 + 512 * 4 + 512 * 4 + (size_t)GG * 512 * 4;
  char* zz = (char*)alloc(zz_bytes);
  int* cnt = (int*)zz;
  float* bnsum = (float*)(zz + (size_t)NN * 4);
  float* bnsumsq = bnsum + 512;
  float* gsum = bnsumsq + 512;
  int* rowptr = (int*)alloc((size_t)(NN + 1) * 4);
  int* csr_src = (int*)alloc((size_t)EE * 4);
  int2* pairs = (int2*)alloc((size_t)EE * 8);
  int* bsum = (int*)alloc(128 * 4);
  int* bcursor = (int*)alloc(512 * 4);
  unsigned short* x16 = (unsigned short*)alloc((size_t)NN * 128 * 2);
  unsigned short* g16a = (unsigned short*)alloc((size_t)NN * 128 * 2);
  unsigned short* emb16 = (unsigned short*)alloc((size_t)NN * 512 * 2);
  unsigned short* WT1 = (unsigned short*)alloc((size_t)LL * 16384 * 2);
  unsigned short* WT2 = (unsigned short*)alloc((size_t)LL * 16384 * 2);
  unsigned short* W1T = (unsigned short*)alloc((size_t)1024 * 256 * 2);
  unsigned short* W2T = (unsigned short*)alloc((size_t)256 * 128 * 2);
  float* b1x = (float*)alloc(256 * 4);

  const int* esrc = edge_index;
  const int* edst = edge_index + EE;
  const int nblk = (NN + 1023) / 1024;   // 98
  const int nech = (EE + 4095) / 4096;   // 391

  hipMemsetAsync(zz, 0, zz_bytes, stream);
  hist_kernel<<<(EE / 4 + 255) / 256, 256, 0, stream>>>(edst, cnt, EE);
  scan_p1<<<nblk, 256, 0, stream>>>(cnt, bsum, NN);
  scan_p2<<<1, 128, 0, stream>>>(bsum, rowptr, nblk, NN);
  scan_p3<<<nblk, 256, 0, stream>>>(cnt, bsum, rowptr, NN);
  bcursor_init<<<(NB2 + 255) / 256, 256, 0, stream>>>(rowptr, bcursor);
  partition_kernel<<<nech, 256, 0, stream>>>(esrc, edst, bcursor, pairs, EE);
  scatter_sort<<<NB2, 256, 0, stream>>>(pairs, rowptr, csr_src);
  convert_all<<<(NF2B + NCVW + 255) / 256, 256, 0, stream>>>(
      x, x16, cW1, cW2, WT1, WT2, epW2, W2T);

  for (int l = 0; l < LL; ++l) {
    const unsigned short* h16 = (l == 0) ? x16 : (emb16 + (size_t)(l - 1) * 128);
    int ld = (l == 0) ? 128 : 512;
    aggregate_bf16<<<(NN + 15) / 16, 256, 0, stream>>>(
        h16, ld, rowptr, csr_src, ceps + l,
        (l == 0) ? nullptr : bnsum + (l - 1) * 128,
        (l == 0) ? nullptr : bnsumsq + (l - 1) * 128,
        (l == 0) ? nullptr : cgamma + (l - 1) * 128,
        (l == 0) ? nullptr : cbeta + (l - 1) * 128,
        g16a, NN);
    trunk_fused<<<(NN + 127) / 128, 256, 0, stream>>>(
        g16a, WT1 + (size_t)l * 16384, cb1 + l * 128,
        WT2 + (size_t)l * 16384, cb2 + l * 128,
        bnsum + l * 128, bnsumsq + l * 128, emb16 + (size_t)l * 128, NN);
  }
  ep_w1_prep<<<256, 256, 0, stream>>>(epW1, epb1, bnsum, bnsumsq, cgamma, cbeta,
                                      W1T, b1x);

  pool_bf16<<<dim3(GG, 8), 256, 0, stream>>>(emb16, batch, gsum);
  nc_fused<<<GG, 256, 0, stream>>>(gsum, batch, bnsum, bnsumsq, cgamma, cbeta,
                                   ncW1, ncb1, ncW2, ncb2, ncW3, ncb3,
                                   ncW4, ncb4, (float*)d_out);

  ep_fused<<<(NC + 127) / 128, 512, 0, stream>>>(
      emb16, cand, W1T, b1x, W2T, epb2, epW3, epb3,
      (float*)d_out + GG * CCLS, NC);
}

// Round 14
// 907.426 us; speedup vs baseline: 1.1444x; 1.0031x over previous
//
#include <hip/hip_runtime.h>
#include <math.h>

#define NN 100000
#define EE 1600000
#define GG 64
#define HH 128
#define LL 4
#define CCLS 16
#define NC 100000
#define NB2 391  // dst buckets of 256 nodes
#define SCAP 6144 // LDS reorder capacity (avg bucket ~4092, +32 sigma)
#define LDK 40   // padded LDS row stride (bf16 elems) for 32-wide K tiles
#define LDA2 136 // padded LDS row stride for full-K (128) tiles
#define LDC 260  // padded stride for the fused C1 tile (dword stride 130 ≡ 2 mod 32: ≤2-way banks)

typedef __attribute__((ext_vector_type(8))) short bf16x8;
typedef __attribute__((ext_vector_type(4))) float f32x4;

__device__ __forceinline__ unsigned short f2bf(float x) {
  union { float f; unsigned int u; } v; v.f = x;
  unsigned int r = v.u + 0x7fffu + ((v.u >> 16) & 1u);
  return (unsigned short)(r >> 16);
}
__device__ __forceinline__ float bl(unsigned u) {
  union { unsigned u; float f; } v; v.u = u << 16; return v.f;
}
__device__ __forceinline__ float bh(unsigned u) {
  union { unsigned u; float f; } v; v.u = u & 0xffff0000u; return v.f;
}

// ---------------- CSR build ----------------
__global__ void hist_kernel(const int* __restrict__ dst, int* __restrict__ cnt, int E) {
  int i = (blockIdx.x * 256 + threadIdx.x) * 4;
  if (i + 3 < E) {
    int4 v = *(const int4*)(dst + i);
    atomicAdd(&cnt[v.x], 1);
    atomicAdd(&cnt[v.y], 1);
    atomicAdd(&cnt[v.z], 1);
    atomicAdd(&cnt[v.w], 1);
  } else {
    for (int k = i; k < E; ++k) atomicAdd(&cnt[dst[k]], 1);
  }
}

__global__ __launch_bounds__(256) void scan_p1(const int* __restrict__ cnt,
                                               int* __restrict__ bsum, int n) {
  __shared__ int red[256];
  int tid = threadIdx.x;
  int base = blockIdx.x * 1024 + tid * 4;
  int s = 0;
  if (base + 3 < n) {
    int4 v = *(const int4*)(cnt + base);
    s = v.x + v.y + v.z + v.w;
  } else {
    for (int i = 0; i < 4; ++i) if (base + i < n) s += cnt[base + i];
  }
  red[tid] = s;
  __syncthreads();
  for (int st = 128; st >= 1; st >>= 1) {
    if (tid < st) red[tid] += red[tid + st];
    __syncthreads();
  }
  if (tid == 0) bsum[blockIdx.x] = red[0];
}

__global__ void scan_p2(int* __restrict__ bsum, int* __restrict__ rowptr, int nb, int n) {
  __shared__ int buf[128];
  int tid = threadIdx.x;
  int v = (tid < nb) ? bsum[tid] : 0;
  buf[tid] = v;
  __syncthreads();
  for (int off = 1; off < 128; off <<= 1) {
    int t = (tid >= off) ? buf[tid - off] : 0;
    __syncthreads();
    buf[tid] += t;
    __syncthreads();
  }
  if (tid < nb) bsum[tid] = buf[tid] - v;
  if (tid == 127) rowptr[n] = buf[127];
}

__global__ __launch_bounds__(256) void scan_p3(const int* __restrict__ cnt,
                                               const int* __restrict__ bsum,
                                               int* __restrict__ rowptr, int n) {
  __shared__ int red[256];
  int tid = threadIdx.x;
  int base = blockIdx.x * 1024 + tid * 4;
  int v[4] = {0, 0, 0, 0};
  if (base + 3 < n) {
    int4 t = *(const int4*)(cnt + base);
    v[0] = t.x; v[1] = t.y; v[2] = t.z; v[3] = t.w;
  } else {
    for (int i = 0; i < 4; ++i) if (base + i < n) v[i] = cnt[base + i];
  }
  int s = v[0] + v[1] + v[2] + v[3];
  red[tid] = s;
  __syncthreads();
  for (int off = 1; off < 256; off <<= 1) {
    int t = (tid >= off) ? red[tid - off] : 0;
    __syncthreads();
    red[tid] += t;
    __syncthreads();
  }
  int run = bsum[blockIdx.x] + red[tid] - s;
  int4 o;
  o.x = run; o.y = run + v[0]; o.z = o.y + v[1]; o.w = o.z + v[2];
  if (base + 3 < n) {
    *(int4*)(rowptr + base) = o;
  } else {
    int oo[4] = {o.x, o.y, o.z, o.w};
    for (int i = 0; i < 4; ++i)
      if (base + i < n) rowptr[base + i] = oo[i];
  }
}

// bucket write-cursors for partition: start of each 256-node bucket region
__global__ void bcursor_init(const int* __restrict__ rowptr, int* __restrict__ bcursor) {
  int b = blockIdx.x * 256 + threadIdx.x;
  if (b < NB2) bcursor[b] = rowptr[b * 256];
}

// Counting-sort pass 1: partition edges into 391 dst-bucket pair regions.
__global__ __launch_bounds__(256) void partition_kernel(const int* __restrict__ src,
                                                        const int* __restrict__ dst,
                                                        int* __restrict__ bcursor,
                                                        int2* __restrict__ pairs, int E) {
  __shared__ int sS[4096];
  __shared__ int sD[4096];
  __shared__ int hist[NB2 + 1];
  __shared__ int base[NB2 + 1];
  int tid = threadIdx.x;
  int base_e = blockIdx.x * 4096;
  int cnt = min(4096, E - base_e);
  for (int h = tid; h < NB2; h += 256) hist[h] = 0;
  for (int i = tid * 4; i < cnt; i += 1024) {
    if (i + 3 < cnt) {
      *(int4*)(sS + i) = *(const int4*)(src + base_e + i);
      *(int4*)(sD + i) = *(const int4*)(dst + base_e + i);
    } else {
      for (int k = i; k < cnt; ++k) { sS[k] = src[base_e + k]; sD[k] = dst[base_e + k]; }
    }
  }
  __syncthreads();
  for (int i = tid; i < cnt; i += 256) atomicAdd(&hist[sD[i] >> 8], 1);
  __syncthreads();
  for (int h = tid; h < NB2; h += 256) {
    base[h] = atomicAdd(&bcursor[h], hist[h]);
    hist[h] = 0;
  }
  __syncthreads();
  for (int i = tid; i < cnt; i += 256) {
    int d = sD[i];
    int b = d >> 8;
    int off = atomicAdd(&hist[b], 1);
    pairs[base[b] + off] = make_int2(sS[i], d);
  }
}

// Counting-sort pass 2: per-bucket LDS reorder, fully coalesced csr writes.
__global__ __launch_bounds__(256) void scatter_sort(const int2* __restrict__ pairs,
                                                    const int* __restrict__ rowptr,
                                                    int* __restrict__ csr_src) {
  __shared__ int lofs[256];
  __shared__ int sbuf[SCAP];
  int b = blockIdx.x;
  int tid = threadIdx.x;
  int n0 = b * 256;
  int nodes = min(256, NN - n0);
  int pstart = rowptr[n0];
  int L = rowptr[n0 + nodes] - pstart;
  if (tid < nodes) lofs[tid] = rowptr[n0 + tid] - pstart;
  __syncthreads();
  if (L <= SCAP) {
    for (int i = tid; i < L; i += 256) {
      int2 p = pairs[pstart + i];
      int pos = atomicAdd(&lofs[p.y - n0], 1);
      sbuf[pos] = p.x;
    }
    __syncthreads();
    for (int i = tid; i < L; i += 256) csr_src[pstart + i] = sbuf[i];
  } else {
    // fallback (never hit for near-uniform edges): direct global scatter
    for (int i = tid; i < L; i += 256) {
      int2 p = pairs[pstart + i];
      int pos = atomicAdd(&lofs[p.y - n0], 1);
      csr_src[pstart + pos] = p.x;
    }
  }
}

// ---------------- merged converts: x -> bf16, WT1/WT2/W2T -> [N][K] bf16 ----
#define NF2B (NN * HH / 4)            // 3,200,000 float4 items
#define NCVW (LL * 16384 + 32768)     // trunk weights + W2T items
__global__ void convert_all(const float* __restrict__ x, unsigned short* __restrict__ x16,
                            const float* __restrict__ cW1, const float* __restrict__ cW2,
                            unsigned short* __restrict__ WT1, unsigned short* __restrict__ WT2,
                            const float* __restrict__ epW2, unsigned short* __restrict__ W2T) {
  int gi = blockIdx.x * 256 + threadIdx.x;
  if (gi < NF2B) {
    float4 v = ((const float4*)x)[gi];
    unsigned short r[4] = {f2bf(v.x), f2bf(v.y), f2bf(v.z), f2bf(v.w)};
    *(uint2*)(x16 + (size_t)gi * 4) = *(uint2*)r;
    return;
  }
  int idx = gi - NF2B;
  if (idx < LL * 16384) {
    int l = idx >> 14, r = idx & 16383, k = r >> 7, n = r & 127;
    WT1[l * 16384 + n * 128 + k] = f2bf(cW1[idx]);
    WT2[l * 16384 + n * 128 + k] = f2bf(cW2[idx]);
  } else if (idx < NCVW) {
    int j = idx - LL * 16384;
    int k = j >> 7, n = j & 127;
    W2T[(size_t)n * 256 + k] = f2bf(epW2[j]);
  }
}

// ---------------- BN-fold of epW1 (runs after all trunk layers) ----------
__global__ __launch_bounds__(256) void ep_w1_prep(
    const float* __restrict__ epW1, const float* __restrict__ epb1,
    const float* __restrict__ bnsum, const float* __restrict__ bnsumsq,
    const float* __restrict__ gamma, const float* __restrict__ beta,
    unsigned short* __restrict__ W1T, float* __restrict__ b1x) {
  __shared__ float red[256];
  int n = blockIdx.x;
  int tid = threadIdx.x;
  const float inv_n = 1.0f / (float)NN;
  int k0 = tid * 4;
  unsigned short w16[4];
  float part = 0.f;
#pragma unroll
  for (int j = 0; j < 4; ++j) {
    int k = k0 + j;
    int c = k & 511;
    float mu = bnsum[c] * inv_n;
    float var = bnsumsq[c] * inv_n - mu * mu;
    float s = rsqrtf(var + 1e-5f) * gamma[c];
    float o = beta[c] - s * mu;
    float w = epW1[(size_t)k * 256 + n];
    w16[j] = f2bf(s * w);
    part += o * w;
  }
  *(uint2*)(W1T + (size_t)n * 1024 + k0) = *(uint2*)w16;
  red[tid] = part;
  __syncthreads();
  for (int st = 128; st >= 1; st >>= 1) {
    if (tid < st) red[tid] += red[tid + st];
    __syncthreads();
  }
  if (tid == 0) b1x[n] = epb1[n] + red[0];
}

// ---------------- GIN aggregate, v3: index-prefetch software pipeline ------
// 4-edge batches; next batch's csr_src indices load while current batch's
// gathers are in flight (removes the L2 index latency from the dependent
// chain). 64-VGPR / 8-waves-per-SIMD preserved.
__global__ __launch_bounds__(256, 8) void aggregate_bf16(
    const unsigned short* __restrict__ h16, int ld,
    const int* __restrict__ rowptr,
    const int* __restrict__ csr_src,
    const float* __restrict__ ceps_l,
    const float* __restrict__ bnsum_prev,
    const float* __restrict__ bnsumsq_prev,
    const float* __restrict__ gamma_prev,
    const float* __restrict__ beta_prev,
    unsigned short* __restrict__ out, int n) {
  int wave = threadIdx.x >> 6;
  int lane = threadIdx.x & 63;
  int sub = lane >> 4;
  int li = lane & 15;
  int node = blockIdx.x * 16 + wave * 4 + sub;
  if (node >= n) return;
  int c8 = li * 8;
  float acc[8] = {};
  int b = rowptr[node], e = rowptr[node + 1];
  int j = b;
  int cur0, cur1, cur2, cur3;
  if (j + 4 <= e) {
    cur0 = csr_src[j]; cur1 = csr_src[j + 1];
    cur2 = csr_src[j + 2]; cur3 = csr_src[j + 3];
  }
  for (; j + 4 <= e; ) {
    int jn = j + 4;
    uint4 u0 = *(const uint4*)(h16 + (size_t)cur0 * ld + c8);
    uint4 u1 = *(const uint4*)(h16 + (size_t)cur1 * ld + c8);
    uint4 u2 = *(const uint4*)(h16 + (size_t)cur2 * ld + c8);
    uint4 u3 = *(const uint4*)(h16 + (size_t)cur3 * ld + c8);
    if (jn + 4 <= e) {   // prefetch next batch's indices under the gathers
      cur0 = csr_src[jn]; cur1 = csr_src[jn + 1];
      cur2 = csr_src[jn + 2]; cur3 = csr_src[jn + 3];
    }
    acc[0] += bl(u0.x); acc[1] += bh(u0.x);
    acc[2] += bl(u0.y); acc[3] += bh(u0.y);
    acc[4] += bl(u0.z); acc[5] += bh(u0.z);
    acc[6] += bl(u0.w); acc[7] += bh(u0.w);
    acc[0] += bl(u1.x); acc[1] += bh(u1.x);
    acc[2] += bl(u1.y); acc[3] += bh(u1.y);
    acc[4] += bl(u1.z); acc[5] += bh(u1.z);
    acc[6] += bl(u1.w); acc[7] += bh(u1.w);
    acc[0] += bl(u2.x); acc[1] += bh(u2.x);
    acc[2] += bl(u2.y); acc[3] += bh(u2.y);
    acc[4] += bl(u2.z); acc[5] += bh(u2.z);
    acc[6] += bl(u2.w); acc[7] += bh(u2.w);
    acc[0] += bl(u3.x); acc[1] += bh(u3.x);
    acc[2] += bl(u3.y); acc[3] += bh(u3.y);
    acc[4] += bl(u3.z); acc[5] += bh(u3.z);
    acc[6] += bl(u3.w); acc[7] += bh(u3.w);
    j = jn;
  }
  for (; j < e; ++j) {
    int s = csr_src[j];
    uint4 u = *(const uint4*)(h16 + (size_t)s * ld + c8);
    acc[0] += bl(u.x); acc[1] += bh(u.x);
    acc[2] += bl(u.y); acc[3] += bh(u.y);
    acc[4] += bl(u.z); acc[5] += bh(u.z);
    acc[6] += bl(u.w); acc[7] += bh(u.w);
  }
  // self-term + BN affine of previous layer (computed late: not live in loop)
  float eps1 = 1.0f + *ceps_l;
  uint4 hu = *(const uint4*)(h16 + (size_t)node * ld + c8);
  acc[0] = fmaf(eps1, bl(hu.x), acc[0]); acc[1] = fmaf(eps1, bh(hu.x), acc[1]);
  acc[2] = fmaf(eps1, bl(hu.y), acc[2]); acc[3] = fmaf(eps1, bh(hu.y), acc[3]);
  acc[4] = fmaf(eps1, bl(hu.z), acc[4]); acc[5] = fmaf(eps1, bh(hu.z), acc[5]);
  acc[6] = fmaf(eps1, bl(hu.w), acc[6]); acc[7] = fmaf(eps1, bh(hu.w), acc[7]);
  float degw = (float)(e - b) + eps1;
  unsigned short o[8];
  if (bnsum_prev) {
    const float inv_n = 1.0f / (float)NN;
#pragma unroll
    for (int k = 0; k < 8; ++k) {
      int c = c8 + k;
      float mu = bnsum_prev[c] * inv_n;
      float var = bnsumsq_prev[c] * inv_n - mu * mu;
      float s = rsqrtf(var + 1e-5f) * gamma_prev[c];
      float off = beta_prev[c] - s * mu;
      o[k] = f2bf(fmaf(s, acc[k], degw * off));
    }
  } else {
#pragma unroll
    for (int k = 0; k < 8; ++k) o[k] = f2bf(acc[k]);
  }
  *(uint4*)(out + (size_t)node * 128 + c8) = *(uint4*)o;
}

// ---------------- fused trunk layer (full-B stage, barrier-free K loops) ----
// Writes RAW z into the emb16 slice via LDS-staged vectorized copy.
__global__ __launch_bounds__(256) void trunk_fused(
    const unsigned short* __restrict__ A16,
    const unsigned short* __restrict__ W1T, const float* __restrict__ b1,
    const unsigned short* __restrict__ W2T, const float* __restrict__ b2,
    float* __restrict__ bnsum, float* __restrict__ bnsumsq,
    unsigned short* __restrict__ C16 /* emb16 slice, row stride 512 */, int M) {
  __shared__ unsigned short As[128 * LDA2];
  __shared__ unsigned short Bs[128 * LDA2];
  const int tid = threadIdx.x;
  const int bm = blockIdx.x * 128;
  const int lane = tid & 63;
  const int wave = tid >> 6;
  const int wr = (wave >> 1) << 6;
  const int wc = (wave & 1) << 6;
  const int ar = tid >> 1;
  const int ah = (tid & 1) << 4;
  int gra = bm + ar; if (gra >= M) gra = M - 1;
  const unsigned short* Arow = A16 + (size_t)gra * 128;
  const unsigned short* B1row = W1T + (size_t)ar * 128;
  const int mrow = lane & 15;
  const int kq = (lane >> 4) << 3;

  {
    uint4 aR[8], bR[8];
#pragma unroll
    for (int i = 0; i < 4; ++i) {
      aR[2 * i]     = *(const uint4*)(Arow + (i << 5) + ah);
      aR[2 * i + 1] = *(const uint4*)(Arow + (i << 5) + ah + 8);
      bR[2 * i]     = *(const uint4*)(B1row + (i << 5) + ah);
      bR[2 * i + 1] = *(const uint4*)(B1row + (i << 5) + ah + 8);
    }
#pragma unroll
    for (int i = 0; i < 4; ++i) {
      *(uint4*)(As + ar * LDA2 + (i << 5) + ah)     = aR[2 * i];
      *(uint4*)(As + ar * LDA2 + (i << 5) + ah + 8) = aR[2 * i + 1];
      *(uint4*)(Bs + ar * LDA2 + (i << 5) + ah)     = bR[2 * i];
      *(uint4*)(Bs + ar * LDA2 + (i << 5) + ah + 8) = bR[2 * i + 1];
    }
  }
  f32x4 acc[4][4] = {};
  __syncthreads();
#pragma unroll
  for (int ks = 0; ks < 4; ++ks) {
    const int k0 = ks << 5;
    bf16x8 af[4], bfv[4];
#pragma unroll
    for (int t = 0; t < 4; ++t)
      af[t] = *(const bf16x8*)(As + (wr + t * 16 + mrow) * LDA2 + k0 + kq);
#pragma unroll
    for (int t = 0; t < 4; ++t)
      bfv[t] = *(const bf16x8*)(Bs + (wc + t * 16 + mrow) * LDA2 + k0 + kq);
#pragma unroll
    for (int mt = 0; mt < 4; ++mt)
#pragma unroll
      for (int nt = 0; nt < 4; ++nt)
        acc[mt][nt] = __builtin_amdgcn_mfma_f32_16x16x32_bf16(af[mt], bfv[nt], acc[mt][nt], 0, 0, 0);
  }
  uint4 w2[8];
  {
    const unsigned short* B2row = W2T + (size_t)ar * 128;
#pragma unroll
    for (int i = 0; i < 4; ++i) {
      w2[2 * i]     = *(const uint4*)(B2row + (i << 5) + ah);
      w2[2 * i + 1] = *(const uint4*)(B2row + (i << 5) + ah + 8);
    }
  }
  __syncthreads();
  const int crow = (lane >> 4) << 2;
  const int ccol = lane & 15;
#pragma unroll
  for (int nt = 0; nt < 4; ++nt) {
    int c = wc + nt * 16 + ccol;
    float bz = b1[c];
#pragma unroll
    for (int mt = 0; mt < 4; ++mt) {
      int rl = wr + mt * 16 + crow;
#pragma unroll
      for (int i = 0; i < 4; ++i)
        As[(rl + i) * LDA2 + c] = f2bf(fmaxf(acc[mt][nt][i] + bz, 0.f));
    }
  }
#pragma unroll
  for (int i = 0; i < 4; ++i) {
    *(uint4*)(Bs + ar * LDA2 + (i << 5) + ah)     = w2[2 * i];
    *(uint4*)(Bs + ar * LDA2 + (i << 5) + ah + 8) = w2[2 * i + 1];
  }
#pragma unroll
  for (int mt = 0; mt < 4; ++mt)
#pragma unroll
    for (int nt = 0; nt < 4; ++nt)
      acc[mt][nt] = (f32x4){0.f, 0.f, 0.f, 0.f};
  __syncthreads();
#pragma unroll
  for (int ks = 0; ks < 4; ++ks) {
    const int k0 = ks << 5;
    bf16x8 af[4], bfv[4];
#pragma unroll
    for (int t = 0; t < 4; ++t)
      af[t] = *(const bf16x8*)(As + (wr + t * 16 + mrow) * LDA2 + k0 + kq);
#pragma unroll
    for (int t = 0; t < 4; ++t)
      bfv[t] = *(const bf16x8*)(Bs + (wc + t * 16 + mrow) * LDA2 + k0 + kq);
#pragma unroll
    for (int mt = 0; mt < 4; ++mt)
#pragma unroll
      for (int nt = 0; nt < 4; ++nt)
        acc[mt][nt] = __builtin_amdgcn_mfma_f32_16x16x32_bf16(af[mt], bfv[nt], acc[mt][nt], 0, 0, 0);
  }
  // ---- epilogue: bn-sums + z -> Bs (LDS), then vectorized global copy ----
  __syncthreads();  // all waves done reading W2 from Bs
#pragma unroll
  for (int nt = 0; nt < 4; ++nt) {
    int c = wc + nt * 16 + ccol;
    float bz = b2[c];
    float s = 0.f, q = 0.f;
#pragma unroll
    for (int mt = 0; mt < 4; ++mt) {
      int rl = wr + mt * 16 + crow;
      int rbase = bm + rl;
#pragma unroll
      for (int i = 0; i < 4; ++i) {
        float v = fmaxf(acc[mt][nt][i] + bz, 0.f);
        Bs[(rl + i) * LDA2 + c] = f2bf(v);
        if (rbase + i < M) { s += v; q += v * v; }
      }
    }
    s += __shfl_xor(s, 16, 64);
    s += __shfl_xor(s, 32, 64);
    q += __shfl_xor(q, 16, 64);
    q += __shfl_xor(q, 32, 64);
    if (lane < 16) {
      atomicAdd(&bnsum[c], s);
      atomicAdd(&bnsumsq[c], q);
    }
  }
  __syncthreads();
  // copy Bs -> C16: 16 lanes/row x uint4 => 256B contiguous per 4-row instr
#pragma unroll
  for (int p = 0; p < 8; ++p) {
    int r = p * 16 + (tid >> 4);
    int q8 = (tid & 15) * 8;
    if (bm + r < M)
      *(uint4*)(C16 + (size_t)(bm + r) * 512 + q8) =
          *(const uint4*)(Bs + r * LDA2 + q8);
  }
}

// ep fully fused (R7 structure, measured ~107 µs — unchanged).
__global__ __launch_bounds__(512, 4) void ep_fused(
    const unsigned short* __restrict__ emb16, const int* __restrict__ cand,
    const unsigned short* __restrict__ W1T /*[256][1024]*/,
    const float* __restrict__ b1,
    const unsigned short* __restrict__ W2T /*[128][256]*/,
    const float* __restrict__ b2, const float* __restrict__ epW3,
    const float* __restrict__ epb3,
    float* __restrict__ out, int M) {
  __shared__ unsigned short smem[128 * LDC];
  __shared__ float sDotA[128];
  __shared__ float sDotB[128];
  unsigned short* const As0 = smem;
  unsigned short* const As1 = smem + 128 * LDK;
  unsigned short* const Bs0 = smem + 2 * 128 * LDK;
  unsigned short* const Bs1 = smem + 2 * 128 * LDK + 256 * LDK;
  const int tid = threadIdx.x;
  const int bm = blockIdx.x * 128;
  const int lane = tid & 63;
  const int wave = tid >> 6;
  const int wr = (wave >> 2) << 6;   // 2 M-strips of 64
  const int wc = (wave & 3) << 6;    // 4 N-strips of 64
  f32x4 acc[4][4] = {};
  const int ar = tid >> 2;
  const int ah = (tid & 3) << 3;
  int gra = bm + ar; if (gra >= M) gra = M - 1;
  const int node0 = cand[gra];
  const int node1 = cand[NC + gra];
  const int br = tid >> 1;
  const int bh8 = (tid & 1) << 4;
  const unsigned short* Brow = W1T + (size_t)br * 1024 + bh8;
  const unsigned short* Arow0 = emb16 + (size_t)node0 * 512 + ah;
  const unsigned short* Arow1 = emb16 + (size_t)node1 * 512 + ah - 512; // +k*32 for k>=16
  const int mrow = lane & 15;
  const int kq = (lane >> 4) << 3;

  auto ldA = [&](int k) -> uint4 {
    const unsigned short* p = (k < 16) ? Arow0 : Arow1;
    return *(const uint4*)(p + (k << 5));
  };
  auto ldB0v = [&](int k) -> uint4 { return *(const uint4*)(Brow + (k << 5)); };
  auto ldB1v = [&](int k) -> uint4 { return *(const uint4*)(Brow + (k << 5) + 8); };
  auto stTile = [&](unsigned short* Ab, unsigned short* Bb, uint4 a, uint4 x0, uint4 x1) {
    *(uint4*)(Ab + ar * LDK + ah) = a;
    *(uint4*)(Bb + br * LDK + bh8) = x0;
    *(uint4*)(Bb + br * LDK + bh8 + 8) = x1;
  };
  auto mma_step = [&](const unsigned short* A, const unsigned short* B) {
    bf16x8 af[4], bfv[4];
#pragma unroll
    for (int t = 0; t < 4; ++t)
      af[t] = *(const bf16x8*)(A + (wr + t * 16 + mrow) * LDK + kq);
#pragma unroll
    for (int t = 0; t < 4; ++t)
      bfv[t] = *(const bf16x8*)(B + (wc + t * 16 + mrow) * LDK + kq);
#pragma unroll
    for (int mt = 0; mt < 4; ++mt)
#pragma unroll
      for (int nt = 0; nt < 4; ++nt)
        acc[mt][nt] = __builtin_amdgcn_mfma_f32_16x16x32_bf16(af[mt], bfv[nt], acc[mt][nt], 0, 0, 0);
  };

  uint4 aA, aB, b0, b1v;
  {
    uint4 a0 = ldA(0), x0 = ldB0v(0), x1 = ldB1v(0);
    stTile(As0, Bs0, a0, x0, x1);
    aA = ldA(1); b0 = ldB0v(1); b1v = ldB1v(1);
    aB = ldA(2);
  }
  __syncthreads();
  for (int it = 0; it < 16; ++it) {
    const int s0 = 2 * it;
    stTile(As1, Bs1, aA, b0, b1v);
    if (s0 + 3 < 32) aA = ldA(s0 + 3);
    if (s0 + 2 < 32) { b0 = ldB0v(s0 + 2); b1v = ldB1v(s0 + 2); }
    mma_step(As0, Bs0);
    __syncthreads();
    const int s1 = s0 + 1;
    if (s1 < 31) {
      stTile(As0, Bs0, aB, b0, b1v);
      if (s1 + 3 < 32) aB = ldA(s1 + 3);
      if (s1 + 2 < 32) { b0 = ldB0v(s1 + 2); b1v = ldB1v(s1 + 2); }
    }
    mma_step(As1, Bs1);
    __syncthreads();
  }

  const int crow = (lane >> 4) << 2;
  const int ccol = lane & 15;
#pragma unroll
  for (int nt = 0; nt < 4; ++nt) {
    int c = wc + nt * 16 + ccol;
    float bz = b1[c];
#pragma unroll
    for (int mt = 0; mt < 4; ++mt) {
      int rl = wr + mt * 16 + crow;
#pragma unroll
      for (int i = 0; i < 4; ++i)
        smem[(rl + i) * LDC + c] = f2bf(fmaxf(acc[mt][nt][i] + bz, 0.f));
    }
  }
  __syncthreads();
  // GEMM2: [128 x 256] @ W2T^T -> [128 x 128]; A from LDS, B from global (L2-hot 64KB).
  const int wr2 = (wave >> 1) << 5;   // 4 M-strips of 32
  const int wc2 = (wave & 1) << 6;    // 2 N-strips of 64
  f32x4 acc2[2][4] = {};
  for (int ks = 0; ks < 8; ++ks) {
    const int k0 = ks << 5;
    bf16x8 af[2], bfv[4];
#pragma unroll
    for (int t = 0; t < 2; ++t)
      af[t] = *(const bf16x8*)(smem + (wr2 + t * 16 + mrow) * LDC + k0 + kq);
#pragma unroll
    for (int t = 0; t < 4; ++t)
      bfv[t] = *(const bf16x8*)(W2T + (size_t)(wc2 + t * 16 + mrow) * 256 + k0 + kq);
#pragma unroll
    for (int mt = 0; mt < 2; ++mt)
#pragma unroll
      for (int nt = 0; nt < 4; ++nt)
        acc2[mt][nt] = __builtin_amdgcn_mfma_f32_16x16x32_bf16(af[mt], bfv[nt], acc2[mt][nt], 0, 0, 0);
  }
  // epilogue: shfl-reduce the 16 ccol partials per row; one store per row.
  float w3v[4], bz2[4];
#pragma unroll
  for (int nt = 0; nt < 4; ++nt) {
    int c = wc2 + nt * 16 + ccol;
    w3v[nt] = epW3[c];
    bz2[nt] = b2[c];
  }
  float* sBank = (wave & 1) ? sDotB : sDotA;
#pragma unroll
  for (int mt = 0; mt < 2; ++mt) {
#pragma unroll
    for (int i = 0; i < 4; ++i) {
      int rl = wr2 + mt * 16 + crow + i;
      float p = 0.f;
#pragma unroll
      for (int nt = 0; nt < 4; ++nt)
        p = fmaf(fmaxf(acc2[mt][nt][i] + bz2[nt], 0.f), w3v[nt], p);
      p += __shfl_xor(p, 1, 64);
      p += __shfl_xor(p, 2, 64);
      p += __shfl_xor(p, 4, 64);
      p += __shfl_xor(p, 8, 64);
      if ((lane & 15) == 0) sBank[rl] = p;
    }
  }
  __syncthreads();
  if (tid < 128) {
    int r = bm + tid;
    if (r < M) out[r] = 1.f / (1.f + expf(-(sDotA[tid] + sDotB[tid] + epb3[0])));
  }
}

// ---------------- pooling (inline graph bounds, vectorized reads) ----------
__global__ __launch_bounds__(256) void pool_bf16(const unsigned short* __restrict__ emb16,
                                                 const int* __restrict__ batch,
                                                 float* __restrict__ gsum) {
  __shared__ int se[2];
  __shared__ float sRed[512];
  int g = blockIdx.x;
  int chunk = blockIdx.y;
  int tid = threadIdx.x;
  if (tid < 2) {
    int x = g + tid;
    int lo = 0, hi = NN;
    while (lo < hi) {
      int mid = (lo + hi) >> 1;
      if (batch[mid] < x) lo = mid + 1; else hi = mid;
    }
    se[tid] = lo;
  }
  __syncthreads();
  int s = se[0], e = se[1];
  int len = e - s;
  int per = (len + 7) >> 3;
  int r0 = s + chunk * per;
  int r1 = min(r0 + per, e);
  int c8 = (tid & 63) * 8;
  int wgrp = tid >> 6;
  float acc[8] = {};
  for (int r = r0 + wgrp; r < r1; r += 4) {
    uint4 u = *(const uint4*)(emb16 + (size_t)r * 512 + c8);
    acc[0] += bl(u.x); acc[1] += bh(u.x);
    acc[2] += bl(u.y); acc[3] += bh(u.y);
    acc[4] += bl(u.z); acc[5] += bh(u.z);
    acc[6] += bl(u.w); acc[7] += bh(u.w);
  }
  if (wgrp == 0) {
#pragma unroll
    for (int j = 0; j < 8; ++j) sRed[c8 + j] = acc[j];
  }
  __syncthreads();
  for (int w = 1; w < 4; ++w) {
    if (wgrp == w) {
#pragma unroll
      for (int j = 0; j < 8; ++j) sRed[c8 + j] += acc[j];
    }
    __syncthreads();
  }
  if (r0 < r1 && tid < 128) {
#pragma unroll
    for (int j = 0; j < 4; ++j)
      atomicAdd(&gsum[g * 512 + tid * 4 + j], sRed[tid * 4 + j]);
  }
}

// ---------------- fused node classifier (inline bounds + BN affine on mean) --
__global__ __launch_bounds__(256) void nc_fused(
    const float* __restrict__ gsum, const int* __restrict__ batch,
    const float* __restrict__ bnsum, const float* __restrict__ bnsumsq,
    const float* __restrict__ gamma, const float* __restrict__ beta,
    const float* __restrict__ W1, const float* __restrict__ b1,
    const float* __restrict__ W2, const float* __restrict__ b2,
    const float* __restrict__ W3, const float* __restrict__ b3,
    const float* __restrict__ W4, const float* __restrict__ b4,
    float* __restrict__ out) {
  __shared__ float row[512];
  __shared__ float t1[256];
  __shared__ float t2[128];
  __shared__ float t3s[128];
  __shared__ float lg[16];
  __shared__ int se[2];
  int g = blockIdx.x;
  int tid = threadIdx.x;
  if (tid < 2) {
    int x = g + tid;
    int lo = 0, hi = NN;
    while (lo < hi) {
      int mid = (lo + hi) >> 1;
      if (batch[mid] < x) lo = mid + 1; else hi = mid;
    }
    se[tid] = lo;
  }
  __syncthreads();
  float inv = 1.0f / fmaxf((float)(se[1] - se[0]), 1.0f);
  const float inv_n = 1.0f / (float)NN;
#pragma unroll
  for (int h = 0; h < 2; ++h) {
    int c = tid + h * 256;
    float mu = bnsum[c] * inv_n;
    float var = bnsumsq[c] * inv_n - mu * mu;
    float s = rsqrtf(var + 1e-5f) * gamma[c];
    float o = beta[c] - s * mu;
    row[c] = fmaf(gsum[g * 512 + c] * inv, s, o);
  }
  __syncthreads();
  {
    float acc = b1[tid];
#pragma unroll 8
    for (int k = 0; k < 512; ++k) acc = fmaf(row[k], W1[k * 256 + tid], acc);
    t1[tid] = fmaxf(acc, 0.f);
  }
  __syncthreads();
  if (tid < 128) {
    float acc = b2[tid];
#pragma unroll 8
    for (int k = 0; k < 256; ++k) acc = fmaf(t1[k], W2[k * 128 + tid], acc);
    t2[tid] = fmaxf(acc, 0.f);
  }
  __syncthreads();
  if (tid < 128) {
    float acc = b3[tid];
#pragma unroll 8
    for (int k = 0; k < 128; ++k) acc = fmaf(t2[k], W3[k * 128 + tid], acc);
    t3s[tid] = fmaxf(acc, 0.f);
  }
  __syncthreads();
  if (tid < 16) {
    float acc = b4[tid];
#pragma unroll 8
    for (int k = 0; k < 128; ++k) acc = fmaf(t3s[k], W4[k * 16 + tid], acc);
    lg[tid] = acc;
  }
  __syncthreads();
  if (tid < 16) {
    float v = lg[tid];
    float m = v;
    for (int j = 0; j < 16; ++j) m = fmaxf(m, lg[j]);
    float s = 0.f;
    for (int j = 0; j < 16; ++j) s += expf(lg[j] - m);
    out[g * 16 + tid] = v - m - logf(s);
  }
}

// ---------------- launch ----------------
extern "C" void kernel_launch(void* const* d_in, const int* in_sizes, int n_in,
                              void* d_out, int out_size, void* d_ws, size_t ws_size,
                              hipStream_t stream) {
  const float* x = (const float*)d_in[0];
  const int* edge_index = (const int*)d_in[1];
  const int* batch = (const int*)d_in[2];
  const int* cand = (const int*)d_in[3];
  const float* cW1 = (const float*)d_in[4];
  const float* cb1 = (const float*)d_in[5];
  const float* cW2 = (const float*)d_in[6];
  const float* cb2 = (const float*)d_in[7];
  const float* cgamma = (const float*)d_in[8];
  const float* cbeta = (const float*)d_in[9];
  const float* ceps = (const float*)d_in[10];
  const float* ncW1 = (const float*)d_in[11];
  const float* ncb1 = (const float*)d_in[12];
  const float* ncW2 = (const float*)d_in[13];
  const float* ncb2 = (const float*)d_in[14];
  const float* ncW3 = (const float*)d_in[15];
  const float* ncb3 = (const float*)d_in[16];
  const float* ncW4 = (const float*)d_in[17];
  const float* ncb4 = (const float*)d_in[18];
  const float* epW1 = (const float*)d_in[19];
  const float* epb1 = (const float*)d_in[20];
  const float* epW2 = (const float*)d_in[21];
  const float* epb2 = (const float*)d_in[22];
  const float* epW3 = (const float*)d_in[23];
  const float* epb3 = (const float*)d_in[24];

  char* ws = (char*)d_ws;
  size_t off = 0;
  auto alloc = [&](size_t bytes) -> void* {
    off = (off + 255) & ~(size_t)255;
    void* p = ws + off;
    off += bytes;
    return p;
  };
  // zero zone: cnt | bnsum | bnsumsq | gsum
  size_t zz_bytes = (size_t)NN * 4 + 512 * 4 + 512 * 4 + (size_t)GG * 512 * 4;
  char* zz = (char*)alloc(zz_bytes);
  int* cnt = (int*)zz;
  float* bnsum = (float*)(zz + (size_t)NN * 4);
  float* bnsumsq = bnsum + 512;
  float* gsum = bnsumsq + 512;
  int* rowptr = (int*)alloc((size_t)(NN + 1) * 4);
  int* csr_src = (int*)alloc((size_t)EE * 4);
  int2* pairs = (int2*)alloc((size_t)EE * 8);
  int* bsum = (int*)alloc(128 * 4);
  int* bcursor = (int*)alloc(512 * 4);
  unsigned short* x16 = (unsigned short*)alloc((size_t)NN * 128 * 2);
  unsigned short* g16a = (unsigned short*)alloc((size_t)NN * 128 * 2);
  unsigned short* emb16 = (unsigned short*)alloc((size_t)NN * 512 * 2);
  unsigned short* WT1 = (unsigned short*)alloc((size_t)LL * 16384 * 2);
  unsigned short* WT2 = (unsigned short*)alloc((size_t)LL * 16384 * 2);
  unsigned short* W1T = (unsigned short*)alloc((size_t)1024 * 256 * 2);
  unsigned short* W2T = (unsigned short*)alloc((size_t)256 * 128 * 2);
  float* b1x = (float*)alloc(256 * 4);

  const int* esrc = edge_index;
  const int* edst = edge_index + EE;
  const int nblk = (NN + 1023) / 1024;   // 98
  const int nech = (EE + 4095) / 4096;   // 391

  hipMemsetAsync(zz, 0, zz_bytes, stream);
  hist_kernel<<<(EE / 4 + 255) / 256, 256, 0, stream>>>(edst, cnt, EE);
  scan_p1<<<nblk, 256, 0, stream>>>(cnt, bsum, NN);
  scan_p2<<<1, 128, 0, stream>>>(bsum, rowptr, nblk, NN);
  scan_p3<<<nblk, 256, 0, stream>>>(cnt, bsum, rowptr, NN);
  bcursor_init<<<(NB2 + 255) / 256, 256, 0, stream>>>(rowptr, bcursor);
  partition_kernel<<<nech, 256, 0, stream>>>(esrc, edst, bcursor, pairs, EE);
  scatter_sort<<<NB2, 256, 0, stream>>>(pairs, rowptr, csr_src);
  convert_all<<<(NF2B + NCVW + 255) / 256, 256, 0, stream>>>(
      x, x16, cW1, cW2, WT1, WT2, epW2, W2T);

  for (int l = 0; l < LL; ++l) {
    const unsigned short* h16 = (l == 0) ? x16 : (emb16 + (size_t)(l - 1) * 128);
    int ld = (l == 0) ? 128 : 512;
    aggregate_bf16<<<(NN + 15) / 16, 256, 0, stream>>>(
        h16, ld, rowptr, csr_src, ceps + l,
        (l == 0) ? nullptr : bnsum + (l - 1) * 128,
        (l == 0) ? nullptr : bnsumsq + (l - 1) * 128,
        (l == 0) ? nullptr : cgamma + (l - 1) * 128,
        (l == 0) ? nullptr : cbeta + (l - 1) * 128,
        g16a, NN);
    trunk_fused<<<(NN + 127) / 128, 256, 0, stream>>>(
        g16a, WT1 + (size_t)l * 16384, cb1 + l * 128,
        WT2 + (size_t)l * 16384, cb2 + l * 128,
        bnsum + l * 128, bnsumsq + l * 128, emb16 + (size_t)l * 128, NN);
  }
  ep_w1_prep<<<256, 256, 0, stream>>>(epW1, epb1, bnsum, bnsumsq, cgamma, cbeta,
                                      W1T, b1x);

  pool_bf16<<<dim3(GG, 8), 256, 0, stream>>>(emb16, batch, gsum);
  nc_fused<<<GG, 256, 0, stream>>>(gsum, batch, bnsum, bnsumsq, cgamma, cbeta,
                                   ncW1, ncb1, ncW2, ncb2, ncW3, ncb3,
                                   ncW4, ncb4, (float*)d_out);

  ep_fused<<<(NC + 127) / 128, 512, 0, stream>>>(
      emb16, cand, W1T, b1x, W2T, epb2, epW3, epb3,
      (float*)d_out + GG * CCLS, NC);
}